// Round 1
// baseline (421.707 us; speedup 1.0000x reference)
//
#include <hip/hip_runtime.h>

#define S_LEN 2048
#define D_DIM 1024
#define NHEAD 16
#define DH 64
#define BATCH 2
#define NROWS (BATCH * S_LEN)  // 4096

typedef __attribute__((ext_vector_type(8))) short short8;
typedef __attribute__((ext_vector_type(4))) float f32x4;

static __device__ __forceinline__ unsigned short f2bf(float f) {
    unsigned int u = __builtin_bit_cast(unsigned int, f);
    u += 0x7fffu + ((u >> 16) & 1u);
    return (unsigned short)(u >> 16);
}

// ---------------- fp32 -> bf16 convert ----------------
__global__ __launch_bounds__(256) void cvt_kernel(const float* __restrict__ src,
                                                  unsigned short* __restrict__ dst, int n4) {
    int i = blockIdx.x * 256 + threadIdx.x;
    if (i < n4) {
        float4 v = ((const float4*)src)[i];
        ushort4 o;
        o.x = f2bf(v.x); o.y = f2bf(v.y); o.z = f2bf(v.z); o.w = f2bf(v.w);
        ((ushort4*)dst)[i] = o;
    }
}

// ---------------- key/query padding masks (exact fp32 row sums) ----------------
__global__ __launch_bounds__(256) void mask_kernel(const float* __restrict__ q,
                                                   const float* __restrict__ k,
                                                   float* __restrict__ qm,
                                                   float* __restrict__ km) {
    const float* src = blockIdx.y ? k : q;
    float* dst = blockIdx.y ? km : qm;
    int row = blockIdx.x;
    float4 v = ((const float4*)(src + (size_t)row * D_DIM))[threadIdx.x];
    float s = v.x + v.y + v.z + v.w;
    for (int o = 1; o < 64; o <<= 1) s += __shfl_xor(s, o);
    __shared__ float red[4];
    int w = threadIdx.x >> 6;
    if ((threadIdx.x & 63) == 0) red[w] = s;
    __syncthreads();
    if (threadIdx.x == 0) {
        float t = red[0] + red[1] + red[2] + red[3];
        dst[row] = (t != 0.0f) ? 1.0f : 0.0f;
    }
}

// ---------------- fused QKV projection: O = relu(A @ W^T + b), bf16 MFMA ----------------
// A: [4096][1024] bf16, W: [1024][1024] bf16 (row-major, used as B^T), O: [4096][1024] bf16
__global__ __launch_bounds__(256) void proj_kernel(
    const unsigned short* __restrict__ A0, const unsigned short* __restrict__ A1,
    const unsigned short* __restrict__ A2, const unsigned short* __restrict__ W0,
    const unsigned short* __restrict__ W1, const unsigned short* __restrict__ W2,
    const float* __restrict__ b0, const float* __restrict__ b1, const float* __restrict__ b2,
    unsigned short* __restrict__ O0, unsigned short* __restrict__ O1,
    unsigned short* __restrict__ O2) {
    const unsigned short* A;
    const unsigned short* W;
    const float* bias;
    unsigned short* O;
    if (blockIdx.z == 0) { A = A0; W = W0; bias = b0; O = O0; }
    else if (blockIdx.z == 1) { A = A1; W = W1; bias = b1; O = O1; }
    else { A = A2; W = W2; bias = b2; O = O2; }

    __shared__ __align__(16) unsigned short Asm[128 * 32];
    __shared__ __align__(16) unsigned short Bsm[128 * 32];

    const int t = threadIdx.x;
    const int w = t >> 6, l = t & 63;
    const int quad = l >> 4, lr = l & 15;
    const int wm = w >> 1, wn = w & 1;
    const int m0 = blockIdx.y * 128, n0 = blockIdx.x * 128;

    f32x4 zero = {0.f, 0.f, 0.f, 0.f};
    f32x4 acc[4][4];
#pragma unroll
    for (int i = 0; i < 4; i++)
#pragma unroll
        for (int j = 0; j < 4; j++) acc[i][j] = zero;

    // staging: chunk c (0..7) = 1KB = rows [c*16, c*16+16) of the 128x32 bf16 tile.
    // lane l covers row c*16 + l/4, cols (l&3)*8 .. +8. LDS dest = chunk base + lane*16.
    const int c0 = w * 2, c1 = w * 2 + 1;
    const int ar0 = c0 * 16 + (l >> 2), ar1 = c1 * 16 + (l >> 2);
    const int acol = (l & 3) * 8;

    for (int kt = 0; kt < D_DIM / 32; ++kt) {
        const int k0 = kt * 32;
        __syncthreads();
        __builtin_amdgcn_global_load_lds(
            (const __attribute__((address_space(1))) void*)(A + (size_t)(m0 + ar0) * D_DIM + k0 + acol),
            (__attribute__((address_space(3))) void*)(&Asm[c0 * 512]), 16, 0, 0);
        __builtin_amdgcn_global_load_lds(
            (const __attribute__((address_space(1))) void*)(A + (size_t)(m0 + ar1) * D_DIM + k0 + acol),
            (__attribute__((address_space(3))) void*)(&Asm[c1 * 512]), 16, 0, 0);
        __builtin_amdgcn_global_load_lds(
            (const __attribute__((address_space(1))) void*)(W + (size_t)(n0 + ar0) * D_DIM + k0 + acol),
            (__attribute__((address_space(3))) void*)(&Bsm[c0 * 512]), 16, 0, 0);
        __builtin_amdgcn_global_load_lds(
            (const __attribute__((address_space(1))) void*)(W + (size_t)(n0 + ar1) * D_DIM + k0 + acol),
            (__attribute__((address_space(3))) void*)(&Bsm[c1 * 512]), 16, 0, 0);
        __syncthreads();

        short8 af[4], bf[4];
#pragma unroll
        for (int i = 0; i < 4; i++)
            af[i] = *(const short8*)&Asm[(wm * 64 + i * 16 + lr) * 32 + quad * 8];
#pragma unroll
        for (int j = 0; j < 4; j++)
            bf[j] = *(const short8*)&Bsm[(wn * 64 + j * 16 + lr) * 32 + quad * 8];
#pragma unroll
        for (int i = 0; i < 4; i++)
#pragma unroll
            for (int j = 0; j < 4; j++)
                acc[i][j] = __builtin_amdgcn_mfma_f32_16x16x32_bf16(af[i], bf[j], acc[i][j], 0, 0, 0);
    }

#pragma unroll
    for (int j = 0; j < 4; j++) {
        const int gn = n0 + wn * 64 + j * 16 + lr;
        const float bj = bias[gn];
#pragma unroll
        for (int i = 0; i < 4; i++) {
            const int gmb = m0 + wm * 64 + i * 16 + quad * 4;
#pragma unroll
            for (int r = 0; r < 4; r++) {
                float v = acc[i][j][r] + bj;
                v = fmaxf(v, 0.f);
                O[(size_t)(gmb + r) * D_DIM + gn] = f2bf(v);
            }
        }
    }
}

// ---------------- V transpose: (B,S,D) bf16 -> (B,H,dh,S) bf16 ----------------
__global__ __launch_bounds__(256) void transpose_v(const unsigned short* __restrict__ Vb,
                                                   unsigned short* __restrict__ Vt) {
    __shared__ unsigned short tile[64][65];
    const int s0 = blockIdx.x * 64, h = blockIdx.y, b = blockIdx.z;
    const int t = threadIdx.x;
#pragma unroll
    for (int p = 0; p < 16; p++) {
        int idx = p * 256 + t;
        int si = idx >> 6, ni = idx & 63;
        tile[si][ni] = Vb[(size_t)(b * S_LEN + s0 + si) * D_DIM + h * DH + ni];
    }
    __syncthreads();
#pragma unroll
    for (int p = 0; p < 16; p++) {
        int idx = p * 256 + t;
        int ni = idx >> 6, si = idx & 63;
        Vt[((size_t)(b * NHEAD + h) * DH + ni) * S_LEN + s0 + si] = tile[si][ni];
    }
}

// ---------------- flash attention, bf16 MFMA, causal + padding masks ----------------
// grid (S/64, H, B), block 256 = 4 waves; wave handles 16 query rows.
__global__ __launch_bounds__(256) void attn_kernel(const unsigned short* __restrict__ Qb,
                                                   const unsigned short* __restrict__ Kb,
                                                   const unsigned short* __restrict__ Vt,
                                                   const float* __restrict__ qmask,
                                                   const float* __restrict__ kmask,
                                                   float* __restrict__ Oout) {
    __shared__ __align__(16) float Pl[4][16 * 36];  // stride 36 fp32: 2-way-max banks, 16B aligned
    const int w = threadIdx.x >> 6, l = threadIdx.x & 63;
    const int quad = l >> 4, lr = l & 15;
    const int q0 = blockIdx.x * 64, h = blockIdx.y, b = blockIdx.z;
    const int qbase = q0 + w * 16;
    const float NEGF = -4294967295.0f;
    const float scale = 0.125f;  // 1/sqrt(64)

    // Q fragments (A-layout): m = lr, k = s*32 + quad*8 + j
    const unsigned short* qptr = Qb + (size_t)(b * S_LEN + qbase + lr) * D_DIM + h * DH + quad * 8;
    const short8 qf0 = *(const short8*)(qptr);
    const short8 qf1 = *(const short8*)(qptr + 32);

    f32x4 zero = {0.f, 0.f, 0.f, 0.f};
    f32x4 o[4];
#pragma unroll
    for (int j = 0; j < 4; j++) o[j] = zero;
    float m_run[4], l_run[4];
#pragma unroll
    for (int r = 0; r < 4; r++) { m_run[r] = -__builtin_inff(); l_run[r] = 0.f; }

    float* myP = Pl[w];
    const int ntiles = (qbase + 16 + 31) >> 5;  // keys < qbase+16 needed (causal)

    for (int kt = 0; kt < ntiles; ++kt) {
        const int k0 = kt * 32;
        // ---- scores: 16q x 32k, two 16-wide N halves ----
        f32x4 sc[2];
#pragma unroll
        for (int h2 = 0; h2 < 2; h2++) {
            const unsigned short* kp =
                Kb + (size_t)(b * S_LEN + k0 + h2 * 16 + lr) * D_DIM + h * DH + quad * 8;
            short8 kf0 = *(const short8*)(kp);
            short8 kf1 = *(const short8*)(kp + 32);
            f32x4 z = zero;
            z = __builtin_amdgcn_mfma_f32_16x16x32_bf16(qf0, kf0, z, 0, 0, 0);
            z = __builtin_amdgcn_mfma_f32_16x16x32_bf16(qf1, kf1, z, 0, 0, 0);
            sc[h2] = z;
        }
        const int key0 = k0 + lr, key1 = k0 + 16 + lr;
        const float km0 = kmask[b * S_LEN + key0];
        const float km1 = kmask[b * S_LEN + key1];

        float p0[4], p1[4], alpha[4];
#pragma unroll
        for (int r = 0; r < 4; r++) {
            const int q = qbase + quad * 4 + r;
            float s0v = (key0 > q || km0 == 0.f) ? NEGF : sc[0][r] * scale;
            float s1v = (key1 > q || km1 == 0.f) ? NEGF : sc[1][r] * scale;
            p0[r] = s0v; p1[r] = s1v;
            float m = fmaxf(s0v, s1v);
            m = fmaxf(m, __shfl_xor(m, 1));
            m = fmaxf(m, __shfl_xor(m, 2));
            m = fmaxf(m, __shfl_xor(m, 4));
            m = fmaxf(m, __shfl_xor(m, 8));
            const float mn = fmaxf(m_run[r], m);  // mn >= NEGF always finite
            alpha[r] = __expf(m_run[r] - mn);
            m_run[r] = mn;
            const float e0 = __expf(p0[r] - mn);
            const float e1 = __expf(p1[r] - mn);
            p0[r] = e0; p1[r] = e1;
            float ts = e0 + e1;
            ts += __shfl_xor(ts, 1);
            ts += __shfl_xor(ts, 2);
            ts += __shfl_xor(ts, 4);
            ts += __shfl_xor(ts, 8);
            l_run[r] = l_run[r] * alpha[r] + ts;
        }
        // ---- P: C-layout -> A-layout via per-wave LDS ----
#pragma unroll
        for (int r = 0; r < 4; r++) {
            myP[(quad * 4 + r) * 36 + lr] = p0[r];
            myP[(quad * 4 + r) * 36 + 16 + lr] = p1[r];
        }
#pragma unroll
        for (int j = 0; j < 4; j++)
#pragma unroll
            for (int r = 0; r < 4; r++) o[j][r] *= alpha[r];

        const float* pr = &myP[lr * 36 + quad * 8];
        const float4 pa = *(const float4*)(pr);
        const float4 pb = *(const float4*)(pr + 4);
        short8 pf;
        pf[0] = (short)f2bf(pa.x); pf[1] = (short)f2bf(pa.y);
        pf[2] = (short)f2bf(pa.z); pf[3] = (short)f2bf(pa.w);
        pf[4] = (short)f2bf(pb.x); pf[5] = (short)f2bf(pb.y);
        pf[6] = (short)f2bf(pb.z); pf[7] = (short)f2bf(pb.w);

        // ---- PV: B-operand from Vt rows (contiguous in k) ----
#pragma unroll
        for (int j = 0; j < 4; j++) {
            const unsigned short* vp =
                Vt + ((size_t)(b * NHEAD + h) * DH + j * 16 + lr) * S_LEN + k0 + quad * 8;
            short8 vf = *(const short8*)vp;
            o[j] = __builtin_amdgcn_mfma_f32_16x16x32_bf16(pf, vf, o[j], 0, 0, 0);
        }
    }

#pragma unroll
    for (int r = 0; r < 4; r++) {
        const int q = qbase + quad * 4 + r;
        const float qm = qmask[b * S_LEN + q];
        const float inv = (l_run[r] > 0.f) ? qm / l_run[r] : 0.f;
#pragma unroll
        for (int j = 0; j < 4; j++) {
            Oout[(size_t)(b * S_LEN + q) * D_DIM + h * DH + j * 16 + lr] = o[j][r] * inv;
        }
    }
}

// ---------------- residual + layernorm (ddof=1, /(std+eps)) ----------------
__global__ __launch_bounds__(256) void ln_kernel(const float* __restrict__ attn,
                                                 const float* __restrict__ queries,
                                                 const float* __restrict__ gamma,
                                                 const float* __restrict__ beta,
                                                 float* __restrict__ out) {
    const int row = blockIdx.x;
    const int t = threadIdx.x;
    const float4 a = ((const float4*)(attn + (size_t)row * D_DIM))[t];
    const float4 qv = ((const float4*)(queries + (size_t)row * D_DIM))[t];
    float4 x;
    x.x = a.x + qv.x; x.y = a.y + qv.y; x.z = a.z + qv.z; x.w = a.w + qv.w;
    float s = x.x + x.y + x.z + x.w;
    float sq = x.x * x.x + x.y * x.y + x.z * x.z + x.w * x.w;
    for (int o = 1; o < 64; o <<= 1) { s += __shfl_xor(s, o); sq += __shfl_xor(sq, o); }
    __shared__ float rs[4], rq[4];
    const int w = t >> 6;
    if ((t & 63) == 0) { rs[w] = s; rq[w] = sq; }
    __syncthreads();
    s = rs[0] + rs[1] + rs[2] + rs[3];
    sq = rq[0] + rq[1] + rq[2] + rq[3];
    const float mean = s * (1.0f / 1024.0f);
    float var = (sq - s * mean) * (1.0f / 1023.0f);
    var = fmaxf(var, 0.f);
    const float inv = 1.0f / (sqrtf(var) + 1e-8f);
    const float4 g = ((const float4*)gamma)[t];
    const float4 bb = ((const float4*)beta)[t];
    float4 y;
    y.x = g.x * (x.x - mean) * inv + bb.x;
    y.y = g.y * (x.y - mean) * inv + bb.y;
    y.z = g.z * (x.z - mean) * inv + bb.z;
    y.w = g.w * (x.w - mean) * inv + bb.w;
    ((float4*)(out + (size_t)row * D_DIM))[t] = y;
}

extern "C" void kernel_launch(void* const* d_in, const int* in_sizes, int n_in, void* d_out,
                              int out_size, void* d_ws, size_t ws_size, hipStream_t stream) {
    const float* queries = (const float*)d_in[0];
    const float* keys = (const float*)d_in[1];
    const float* values = (const float*)d_in[2];
    const float* Wq = (const float*)d_in[3];
    const float* bq = (const float*)d_in[4];
    const float* Wk = (const float*)d_in[5];
    const float* bk = (const float*)d_in[6];
    const float* Wv = (const float*)d_in[7];
    const float* bv = (const float*)d_in[8];
    const float* gamma = (const float*)d_in[9];
    const float* beta = (const float*)d_in[10];
    float* out = (float*)d_out;
    char* ws = (char*)d_ws;

    const size_t MB = 1048576;
    unsigned short* qin = (unsigned short*)(ws + 0);        // 8MB, dead after proj
    unsigned short* kin = (unsigned short*)(ws + 8 * MB);   // 8MB, dead after proj
    unsigned short* vin = (unsigned short*)(ws + 16 * MB);  // 8MB, dead after proj
    unsigned short* wqb = (unsigned short*)(ws + 24 * MB);  // 2MB
    unsigned short* wkb = (unsigned short*)(ws + 26 * MB);  // 2MB
    unsigned short* wvb = (unsigned short*)(ws + 28 * MB);  // 2MB
    unsigned short* Qb = (unsigned short*)(ws + 30 * MB);   // 8MB
    unsigned short* Kb = (unsigned short*)(ws + 38 * MB);   // 8MB
    unsigned short* Vb = (unsigned short*)(ws + 46 * MB);   // 8MB
    unsigned short* Vt = (unsigned short*)(ws + 0);         // aliases qin (dead by then)
    float* attn_o = (float*)(ws + 8 * MB);                  // 16MB, aliases kin+vin (dead)
    float* qm = (float*)(ws + 54 * MB);
    float* km = (float*)(ws + 54 * MB + 16384);

    const int n4_in = NROWS * D_DIM / 4;   // 1048576
    const int n4_w = D_DIM * D_DIM / 4;    // 262144

    cvt_kernel<<<n4_in / 256, 256, 0, stream>>>(queries, qin, n4_in);
    cvt_kernel<<<n4_in / 256, 256, 0, stream>>>(keys, kin, n4_in);
    cvt_kernel<<<n4_in / 256, 256, 0, stream>>>(values, vin, n4_in);
    cvt_kernel<<<n4_w / 256, 256, 0, stream>>>(Wq, wqb, n4_w);
    cvt_kernel<<<n4_w / 256, 256, 0, stream>>>(Wk, wkb, n4_w);
    cvt_kernel<<<n4_w / 256, 256, 0, stream>>>(Wv, wvb, n4_w);

    mask_kernel<<<dim3(NROWS, 2), 256, 0, stream>>>(queries, keys, qm, km);

    proj_kernel<<<dim3(D_DIM / 128, NROWS / 128, 3), 256, 0, stream>>>(
        qin, kin, vin, wqb, wkb, wvb, bq, bk, bv, Qb, Kb, Vb);

    transpose_v<<<dim3(S_LEN / 64, NHEAD, BATCH), 256, 0, stream>>>(Vb, Vt);

    attn_kernel<<<dim3(S_LEN / 64, NHEAD, BATCH), 256, 0, stream>>>(Qb, Kb, Vt, qm, km, attn_o);

    ln_kernel<<<NROWS, 256, 0, stream>>>(attn_o, queries, gamma, beta, out);
}

// Round 2
// 304.126 us; speedup vs baseline: 1.3866x; 1.3866x over previous
//
#include <hip/hip_runtime.h>

#define S_LEN 2048
#define D_DIM 1024
#define NHEAD 16
#define DH 64
#define BATCH 2
#define NROWS (BATCH * S_LEN)  // 4096

typedef __attribute__((ext_vector_type(8))) short short8;
typedef __attribute__((ext_vector_type(4))) float f32x4;

static __device__ __forceinline__ unsigned short f2bf(float f) {
    unsigned int u = __builtin_bit_cast(unsigned int, f);
    u += 0x7fffu + ((u >> 16) & 1u);
    return (unsigned short)(u >> 16);
}

// ---------------- fp32 -> bf16 convert, 3 tensors per launch ----------------
__global__ __launch_bounds__(256) void cvt3_kernel(const float* __restrict__ s0,
                                                   const float* __restrict__ s1,
                                                   const float* __restrict__ s2,
                                                   unsigned short* __restrict__ d0,
                                                   unsigned short* __restrict__ d1,
                                                   unsigned short* __restrict__ d2, int n4) {
    const float* src = blockIdx.y == 0 ? s0 : (blockIdx.y == 1 ? s1 : s2);
    unsigned short* dst = blockIdx.y == 0 ? d0 : (blockIdx.y == 1 ? d1 : d2);
    int i = blockIdx.x * 256 + threadIdx.x;
    if (i < n4) {
        float4 v = ((const float4*)src)[i];
        ushort4 o;
        o.x = f2bf(v.x); o.y = f2bf(v.y); o.z = f2bf(v.z); o.w = f2bf(v.w);
        ((ushort4*)dst)[i] = o;
    }
}

// ---------------- padding masks (exact fp32 row sums) ----------------
// qm: multiplicative 0/1.  km: additive penalty 0 / NEG.
__global__ __launch_bounds__(256) void mask_kernel(const float* __restrict__ q,
                                                   const float* __restrict__ k,
                                                   float* __restrict__ qm,
                                                   float* __restrict__ km) {
    const float* src = blockIdx.y ? k : q;
    int row = blockIdx.x;
    float4 v = ((const float4*)(src + (size_t)row * D_DIM))[threadIdx.x];
    float s = v.x + v.y + v.z + v.w;
    for (int o = 1; o < 64; o <<= 1) s += __shfl_xor(s, o);
    __shared__ float red[4];
    int w = threadIdx.x >> 6;
    if ((threadIdx.x & 63) == 0) red[w] = s;
    __syncthreads();
    if (threadIdx.x == 0) {
        float t = red[0] + red[1] + red[2] + red[3];
        if (blockIdx.y)
            km[row] = (t != 0.0f) ? 0.0f : -4294967295.0f;
        else
            qm[row] = (t != 0.0f) ? 1.0f : 0.0f;
    }
}

// ---------------- fused QKV projection: O = relu(A @ W^T + b), bf16 MFMA ----------------
__global__ __launch_bounds__(256) void proj_kernel(
    const unsigned short* __restrict__ A0, const unsigned short* __restrict__ A1,
    const unsigned short* __restrict__ A2, const unsigned short* __restrict__ W0,
    const unsigned short* __restrict__ W1, const unsigned short* __restrict__ W2,
    const float* __restrict__ b0, const float* __restrict__ b1, const float* __restrict__ b2,
    unsigned short* __restrict__ O0, unsigned short* __restrict__ O1,
    unsigned short* __restrict__ O2) {
    const unsigned short* A;
    const unsigned short* W;
    const float* bias;
    unsigned short* O;
    if (blockIdx.z == 0) { A = A0; W = W0; bias = b0; O = O0; }
    else if (blockIdx.z == 1) { A = A1; W = W1; bias = b1; O = O1; }
    else { A = A2; W = W2; bias = b2; O = O2; }

    __shared__ __align__(16) unsigned short Asm[128 * 32];
    __shared__ __align__(16) unsigned short Bsm[128 * 32];

    const int t = threadIdx.x;
    const int w = t >> 6, l = t & 63;
    const int quad = l >> 4, lr = l & 15;
    const int wm = w >> 1, wn = w & 1;
    const int m0 = blockIdx.y * 128, n0 = blockIdx.x * 128;

    f32x4 zero = {0.f, 0.f, 0.f, 0.f};
    f32x4 acc[4][4];
#pragma unroll
    for (int i = 0; i < 4; i++)
#pragma unroll
        for (int j = 0; j < 4; j++) acc[i][j] = zero;

    const int c0 = w * 2, c1 = w * 2 + 1;
    const int ar0 = c0 * 16 + (l >> 2), ar1 = c1 * 16 + (l >> 2);
    const int acol = (l & 3) * 8;

    for (int kt = 0; kt < D_DIM / 32; ++kt) {
        const int k0 = kt * 32;
        __syncthreads();
        __builtin_amdgcn_global_load_lds(
            (const __attribute__((address_space(1))) void*)(A + (size_t)(m0 + ar0) * D_DIM + k0 + acol),
            (__attribute__((address_space(3))) void*)(&Asm[c0 * 512]), 16, 0, 0);
        __builtin_amdgcn_global_load_lds(
            (const __attribute__((address_space(1))) void*)(A + (size_t)(m0 + ar1) * D_DIM + k0 + acol),
            (__attribute__((address_space(3))) void*)(&Asm[c1 * 512]), 16, 0, 0);
        __builtin_amdgcn_global_load_lds(
            (const __attribute__((address_space(1))) void*)(W + (size_t)(n0 + ar0) * D_DIM + k0 + acol),
            (__attribute__((address_space(3))) void*)(&Bsm[c0 * 512]), 16, 0, 0);
        __builtin_amdgcn_global_load_lds(
            (const __attribute__((address_space(1))) void*)(W + (size_t)(n0 + ar1) * D_DIM + k0 + acol),
            (__attribute__((address_space(3))) void*)(&Bsm[c1 * 512]), 16, 0, 0);
        __syncthreads();

        short8 af[4], bf[4];
#pragma unroll
        for (int i = 0; i < 4; i++)
            af[i] = *(const short8*)&Asm[(wm * 64 + i * 16 + lr) * 32 + quad * 8];
#pragma unroll
        for (int j = 0; j < 4; j++)
            bf[j] = *(const short8*)&Bsm[(wn * 64 + j * 16 + lr) * 32 + quad * 8];
#pragma unroll
        for (int i = 0; i < 4; i++)
#pragma unroll
            for (int j = 0; j < 4; j++)
                acc[i][j] = __builtin_amdgcn_mfma_f32_16x16x32_bf16(af[i], bf[j], acc[i][j], 0, 0, 0);
    }

#pragma unroll
    for (int j = 0; j < 4; j++) {
        const int gn = n0 + wn * 64 + j * 16 + lr;
        const float bj = bias[gn];
#pragma unroll
        for (int i = 0; i < 4; i++) {
            const int gmb = m0 + wm * 64 + i * 16 + quad * 4;
#pragma unroll
            for (int r = 0; r < 4; r++) {
                float v = acc[i][j][r] + bj;
                v = fmaxf(v, 0.f);
                O[(size_t)(gmb + r) * D_DIM + gn] = f2bf(v);
            }
        }
    }
}

// ---------------- V transpose: (B,S,D) bf16 -> (B,H,dh,S) bf16 ----------------
__global__ __launch_bounds__(256) void transpose_v(const unsigned short* __restrict__ Vb,
                                                   unsigned short* __restrict__ Vt) {
    __shared__ unsigned short tile[64][65];
    const int s0 = blockIdx.x * 64, h = blockIdx.y, b = blockIdx.z;
    const int t = threadIdx.x;
#pragma unroll
    for (int p = 0; p < 16; p++) {
        int idx = p * 256 + t;
        int si = idx >> 6, ni = idx & 63;
        tile[si][ni] = Vb[(size_t)(b * S_LEN + s0 + si) * D_DIM + h * DH + ni];
    }
    __syncthreads();
#pragma unroll
    for (int p = 0; p < 16; p++) {
        int idx = p * 256 + t;
        int ni = idx >> 6, si = idx & 63;
        Vt[((size_t)(b * NHEAD + h) * DH + ni) * S_LEN + s0 + si] = tile[si][ni];
    }
}

// ---------------- flash attention: LDS-staged shared K/V, double-buffered ----------------
// grid (S/64, H, B), block 256 = 4 waves; wave handles 16 query rows; 64-key tiles.
// K/V tiles stored as 16B chunks with XOR swizzle: chunk(key,cb) at index key*8 + (cb^(key&7)).
__global__ __launch_bounds__(256) void attn_kernel(const unsigned short* __restrict__ Qb,
                                                   const unsigned short* __restrict__ Kb,
                                                   const unsigned short* __restrict__ Vt,
                                                   const float* __restrict__ qmask,
                                                   const float* __restrict__ km_pen,
                                                   float* __restrict__ Oout) {
    __shared__ __align__(16) unsigned short Ks[2][64 * 64];
    __shared__ __align__(16) unsigned short Vs[2][64 * 64];
    __shared__ __align__(16) float Pl[4][16 * 68];  // row stride 68 floats (16B-aligned, conflict-lite)

    const int w = threadIdx.x >> 6, l = threadIdx.x & 63;
    const int quad = l >> 4, lr = l & 15;
    const int q0 = blockIdx.x * 64, h = blockIdx.y, b = blockIdx.z;
    const int qbase = q0 + w * 16;
    const float NEGF = -4294967295.0f;
    const float scale = 0.125f;  // 1/sqrt(64)

    // staging chunk geometry for this lane (wave w stages chunks [w*128, w*128+128))
    const int cA = w * 128 + l;          // issue 0 chunk
    const int cB = w * 128 + 64 + l;     // issue 1 chunk
    const int keyA = cA >> 3, cbA = (cA & 7) ^ (keyA & 7);
    const int keyB = cB >> 3, cbB = (cB & 7) ^ (keyB & 7);
    const unsigned short* Krow = Kb + (size_t)b * S_LEN * D_DIM + h * DH;
    const unsigned short* Vrow = Vt + (size_t)(b * NHEAD + h) * DH * S_LEN;

    // Q fragments (A-layout): m = lr, k = s*32 + quad*8 + j
    const unsigned short* qptr = Qb + (size_t)(b * S_LEN + qbase + lr) * D_DIM + h * DH + quad * 8;
    const short8 qf0 = *(const short8*)(qptr);
    const short8 qf1 = *(const short8*)(qptr + 32);

    f32x4 zero = {0.f, 0.f, 0.f, 0.f};
    f32x4 o[4];
#pragma unroll
    for (int j = 0; j < 4; j++) o[j] = zero;
    float m_run[4], l_run[4];
#pragma unroll
    for (int r = 0; r < 4; r++) { m_run[r] = -__builtin_inff(); l_run[r] = 0.f; }

    float* myP = Pl[w];
    const int swz0 = quad ^ (lr & 7);        // cb swizzle for s=0 reads
    const int swz1 = (quad + 4) ^ (lr & 7);  // cb swizzle for s=1 reads
    const int ntiles = q0 / 64 + 1;          // 64-key tiles up to q0+63

    auto stage = [&](int k0, int bufIdx) {
        __builtin_amdgcn_global_load_lds(
            (const __attribute__((address_space(1))) void*)(Krow + (size_t)(k0 + keyA) * D_DIM + cbA * 8),
            (__attribute__((address_space(3))) void*)(&Ks[bufIdx][(w * 128) * 8]), 16, 0, 0);
        __builtin_amdgcn_global_load_lds(
            (const __attribute__((address_space(1))) void*)(Krow + (size_t)(k0 + keyB) * D_DIM + cbB * 8),
            (__attribute__((address_space(3))) void*)(&Ks[bufIdx][(w * 128 + 64) * 8]), 16, 0, 0);
        __builtin_amdgcn_global_load_lds(
            (const __attribute__((address_space(1))) void*)(Vrow + (size_t)keyA * S_LEN + k0 + cbA * 8),
            (__attribute__((address_space(3))) void*)(&Vs[bufIdx][(w * 128) * 8]), 16, 0, 0);
        __builtin_amdgcn_global_load_lds(
            (const __attribute__((address_space(1))) void*)(Vrow + (size_t)keyB * S_LEN + k0 + cbB * 8),
            (__attribute__((address_space(3))) void*)(&Vs[bufIdx][(w * 128 + 64) * 8]), 16, 0, 0);
    };

    stage(0, 0);
    __syncthreads();

    for (int kt = 0; kt < ntiles; ++kt) {
        const int k0 = kt * 64;
        const int cur = kt & 1;
        if (kt + 1 < ntiles) stage(k0 + 64, cur ^ 1);

        // kmask penalties (additive), issued early to overlap
        float kmv[4];
#pragma unroll
        for (int nf = 0; nf < 4; nf++) kmv[nf] = km_pen[b * S_LEN + k0 + nf * 16 + lr];

        // ---- scores: 16q x 64k ----
        f32x4 sc[4];
#pragma unroll
        for (int nf = 0; nf < 4; nf++) {
            const int key = nf * 16 + lr;
            const short8 kf0 = *(const short8*)&Ks[cur][(key * 8 + swz0) * 8];
            const short8 kf1 = *(const short8*)&Ks[cur][(key * 8 + swz1) * 8];
            f32x4 z = zero;
            z = __builtin_amdgcn_mfma_f32_16x16x32_bf16(qf0, kf0, z, 0, 0, 0);
            z = __builtin_amdgcn_mfma_f32_16x16x32_bf16(qf1, kf1, z, 0, 0, 0);
            sc[nf] = z;
        }

        // ---- online softmax ----
        float alpha[4];
#pragma unroll
        for (int r = 0; r < 4; r++) {
            const int q = qbase + quad * 4 + r;
            float v0 = (k0 + lr <= q) ? sc[0][r] * scale + kmv[0] : NEGF;
            float v1 = (k0 + 16 + lr <= q) ? sc[1][r] * scale + kmv[1] : NEGF;
            float v2 = (k0 + 32 + lr <= q) ? sc[2][r] * scale + kmv[2] : NEGF;
            float v3 = (k0 + 48 + lr <= q) ? sc[3][r] * scale + kmv[3] : NEGF;
            float mx = fmaxf(fmaxf(v0, v1), fmaxf(v2, v3));
            mx = fmaxf(mx, __shfl_xor(mx, 1));
            mx = fmaxf(mx, __shfl_xor(mx, 2));
            mx = fmaxf(mx, __shfl_xor(mx, 4));
            mx = fmaxf(mx, __shfl_xor(mx, 8));
            const float mn = fmaxf(m_run[r], mx);
            const float al = __expf(m_run[r] - mn);
            m_run[r] = mn;
            const float e0 = __expf(v0 - mn);
            const float e1 = __expf(v1 - mn);
            const float e2 = __expf(v2 - mn);
            const float e3 = __expf(v3 - mn);
            float ts = (e0 + e1) + (e2 + e3);
            ts += __shfl_xor(ts, 1);
            ts += __shfl_xor(ts, 2);
            ts += __shfl_xor(ts, 4);
            ts += __shfl_xor(ts, 8);
            l_run[r] = l_run[r] * al + ts;
            alpha[r] = al;
            const int prow = (quad * 4 + r) * 68;
            myP[prow + lr] = e0;
            myP[prow + 16 + lr] = e1;
            myP[prow + 32 + lr] = e2;
            myP[prow + 48 + lr] = e3;
        }

#pragma unroll
        for (int j = 0; j < 4; j++)
#pragma unroll
            for (int r = 0; r < 4; r++) o[j][r] *= alpha[r];

        // ---- P (C-layout) -> A-layout via per-wave LDS, then PV ----
        const float* pr = &myP[lr * 68];
#pragma unroll
        for (int s = 0; s < 2; s++) {
            const float4 pa = *(const float4*)(pr + s * 32 + quad * 8);
            const float4 pb = *(const float4*)(pr + s * 32 + quad * 8 + 4);
            short8 pf;
            pf[0] = (short)f2bf(pa.x); pf[1] = (short)f2bf(pa.y);
            pf[2] = (short)f2bf(pa.z); pf[3] = (short)f2bf(pa.w);
            pf[4] = (short)f2bf(pb.x); pf[5] = (short)f2bf(pb.y);
            pf[6] = (short)f2bf(pb.z); pf[7] = (short)f2bf(pb.w);
            const int swz = s ? swz1 : swz0;
#pragma unroll
            for (int j = 0; j < 4; j++) {
                const int n = j * 16 + lr;
                const short8 vf = *(const short8*)&Vs[cur][(n * 8 + swz) * 8];
                o[j] = __builtin_amdgcn_mfma_f32_16x16x32_bf16(pf, vf, o[j], 0, 0, 0);
            }
        }
        __syncthreads();
    }

#pragma unroll
    for (int r = 0; r < 4; r++) {
        const int q = qbase + quad * 4 + r;
        const float qm = qmask[b * S_LEN + q];
        const float inv = (l_run[r] > 0.f) ? qm / l_run[r] : 0.f;
#pragma unroll
        for (int j = 0; j < 4; j++) {
            Oout[(size_t)(b * S_LEN + q) * D_DIM + h * DH + j * 16 + lr] = o[j][r] * inv;
        }
    }
}

// ---------------- residual + layernorm (ddof=1, /(std+eps)) ----------------
__global__ __launch_bounds__(256) void ln_kernel(const float* __restrict__ attn,
                                                 const float* __restrict__ queries,
                                                 const float* __restrict__ gamma,
                                                 const float* __restrict__ beta,
                                                 float* __restrict__ out) {
    const int row = blockIdx.x;
    const int t = threadIdx.x;
    const float4 a = ((const float4*)(attn + (size_t)row * D_DIM))[t];
    const float4 qv = ((const float4*)(queries + (size_t)row * D_DIM))[t];
    float4 x;
    x.x = a.x + qv.x; x.y = a.y + qv.y; x.z = a.z + qv.z; x.w = a.w + qv.w;
    float s = x.x + x.y + x.z + x.w;
    float sq = x.x * x.x + x.y * x.y + x.z * x.z + x.w * x.w;
    for (int o = 1; o < 64; o <<= 1) { s += __shfl_xor(s, o); sq += __shfl_xor(sq, o); }
    __shared__ float rs[4], rq[4];
    const int w = t >> 6;
    if ((t & 63) == 0) { rs[w] = s; rq[w] = sq; }
    __syncthreads();
    s = rs[0] + rs[1] + rs[2] + rs[3];
    sq = rq[0] + rq[1] + rq[2] + rq[3];
    const float mean = s * (1.0f / 1024.0f);
    float var = (sq - s * mean) * (1.0f / 1023.0f);
    var = fmaxf(var, 0.f);
    const float inv = 1.0f / (sqrtf(var) + 1e-8f);
    const float4 g = ((const float4*)gamma)[t];
    const float4 bb = ((const float4*)beta)[t];
    float4 y;
    y.x = g.x * (x.x - mean) * inv + bb.x;
    y.y = g.y * (x.y - mean) * inv + bb.y;
    y.z = g.z * (x.z - mean) * inv + bb.z;
    y.w = g.w * (x.w - mean) * inv + bb.w;
    ((float4*)(out + (size_t)row * D_DIM))[t] = y;
}

extern "C" void kernel_launch(void* const* d_in, const int* in_sizes, int n_in, void* d_out,
                              int out_size, void* d_ws, size_t ws_size, hipStream_t stream) {
    const float* queries = (const float*)d_in[0];
    const float* keys = (const float*)d_in[1];
    const float* values = (const float*)d_in[2];
    const float* Wq = (const float*)d_in[3];
    const float* bq = (const float*)d_in[4];
    const float* Wk = (const float*)d_in[5];
    const float* bk = (const float*)d_in[6];
    const float* Wv = (const float*)d_in[7];
    const float* bv = (const float*)d_in[8];
    const float* gamma = (const float*)d_in[9];
    const float* beta = (const float*)d_in[10];
    float* out = (float*)d_out;
    char* ws = (char*)d_ws;

    const size_t MB = 1048576;
    unsigned short* qin = (unsigned short*)(ws + 0);        // 8MB, dead after proj
    unsigned short* kin = (unsigned short*)(ws + 8 * MB);   // 8MB, dead after proj
    unsigned short* vin = (unsigned short*)(ws + 16 * MB);  // 8MB, dead after proj
    unsigned short* wqb = (unsigned short*)(ws + 24 * MB);  // 2MB
    unsigned short* wkb = (unsigned short*)(ws + 26 * MB);  // 2MB
    unsigned short* wvb = (unsigned short*)(ws + 28 * MB);  // 2MB
    unsigned short* Qb = (unsigned short*)(ws + 30 * MB);   // 8MB
    unsigned short* Kb = (unsigned short*)(ws + 38 * MB);   // 8MB
    unsigned short* Vb = (unsigned short*)(ws + 46 * MB);   // 8MB
    unsigned short* Vt = (unsigned short*)(ws + 0);         // aliases qin (dead by then)
    float* attn_o = (float*)(ws + 8 * MB);                  // 16MB, aliases kin+vin (dead)
    float* qm = (float*)(ws + 54 * MB);
    float* km = (float*)(ws + 54 * MB + 16384);

    const int n4_in = NROWS * D_DIM / 4;   // 1048576
    const int n4_w = D_DIM * D_DIM / 4;    // 262144

    cvt3_kernel<<<dim3(n4_in / 256, 3), 256, 0, stream>>>(queries, keys, values, qin, kin, vin, n4_in);
    cvt3_kernel<<<dim3(n4_w / 256, 3), 256, 0, stream>>>(Wq, Wk, Wv, wqb, wkb, wvb, n4_w);

    mask_kernel<<<dim3(NROWS, 2), 256, 0, stream>>>(queries, keys, qm, km);

    proj_kernel<<<dim3(D_DIM / 128, NROWS / 128, 3), 256, 0, stream>>>(
        qin, kin, vin, wqb, wkb, wvb, bq, bk, bv, Qb, Kb, Vb);

    transpose_v<<<dim3(S_LEN / 64, NHEAD, BATCH), 256, 0, stream>>>(Vb, Vt);

    attn_kernel<<<dim3(S_LEN / 64, NHEAD, BATCH), 256, 0, stream>>>(Qb, Kb, Vt, qm, km, attn_o);

    ln_kernel<<<NROWS, 256, 0, stream>>>(attn_o, queries, gamma, beta, out);
}

// Round 3
// 248.668 us; speedup vs baseline: 1.6959x; 1.2230x over previous
//
#include <hip/hip_runtime.h>

#define S_LEN 2048
#define D_DIM 1024
#define NHEAD 16
#define DH 64
#define BATCH 2
#define NROWS (BATCH * S_LEN)  // 4096

typedef __attribute__((ext_vector_type(8))) short short8;
typedef __attribute__((ext_vector_type(4))) float f32x4;

static __device__ __forceinline__ unsigned short f2bf(float f) {
    unsigned int u = __builtin_bit_cast(unsigned int, f);
    u += 0x7fffu + ((u >> 16) & 1u);
    return (unsigned short)(u >> 16);
}
static __device__ __forceinline__ float bf2f(unsigned short h) {
    unsigned int u = ((unsigned int)h) << 16;
    return __builtin_bit_cast(float, u);
}

// ---------------- fp32 -> bf16 convert for q/k/v + fused padding masks ----------------
// grid (4096, 3): block = one row (256 thr x float4). y=0 queries (writes qm), y=1 keys
// (writes km additive penalty), y=2 values.
__global__ __launch_bounds__(256) void cvt3_mask_kernel(
    const float* __restrict__ s0, const float* __restrict__ s1, const float* __restrict__ s2,
    unsigned short* __restrict__ d0, unsigned short* __restrict__ d1,
    unsigned short* __restrict__ d2, float* __restrict__ qm, float* __restrict__ km) {
    const int y = blockIdx.y;
    const float* src = y == 0 ? s0 : (y == 1 ? s1 : s2);
    unsigned short* dst = y == 0 ? d0 : (y == 1 ? d1 : d2);
    const int row = blockIdx.x;
    const int t = threadIdx.x;
    const size_t i = (size_t)row * 256 + t;
    float4 v = ((const float4*)src)[i];
    ushort4 o;
    o.x = f2bf(v.x); o.y = f2bf(v.y); o.z = f2bf(v.z); o.w = f2bf(v.w);
    ((ushort4*)dst)[i] = o;
    if (y < 2) {
        float s = v.x + v.y + v.z + v.w;
        for (int off = 1; off < 64; off <<= 1) s += __shfl_xor(s, off);
        __shared__ float red[4];
        const int w = t >> 6;
        if ((t & 63) == 0) red[w] = s;
        __syncthreads();
        if (t == 0) {
            float tt = red[0] + red[1] + red[2] + red[3];
            if (y == 0)
                qm[row] = (tt != 0.0f) ? 1.0f : 0.0f;
            else
                km[row] = (tt != 0.0f) ? 0.0f : -4294967295.0f;
        }
    }
}

// ---------------- fp32 -> bf16 convert, 3 tensors (weights) ----------------
__global__ __launch_bounds__(256) void cvt3_kernel(const float* __restrict__ s0,
                                                   const float* __restrict__ s1,
                                                   const float* __restrict__ s2,
                                                   unsigned short* __restrict__ d0,
                                                   unsigned short* __restrict__ d1,
                                                   unsigned short* __restrict__ d2, int n4) {
    const float* src = blockIdx.y == 0 ? s0 : (blockIdx.y == 1 ? s1 : s2);
    unsigned short* dst = blockIdx.y == 0 ? d0 : (blockIdx.y == 1 ? d1 : d2);
    int i = blockIdx.x * 256 + threadIdx.x;
    if (i < n4) {
        float4 v = ((const float4*)src)[i];
        ushort4 o;
        o.x = f2bf(v.x); o.y = f2bf(v.y); o.z = f2bf(v.z); o.w = f2bf(v.w);
        ((ushort4*)dst)[i] = o;
    }
}

// ---------------- fused QKV projection: O = relu(A @ W^T + b), bf16 MFMA ----------------
__global__ __launch_bounds__(256) void proj_kernel(
    const unsigned short* __restrict__ A0, const unsigned short* __restrict__ A1,
    const unsigned short* __restrict__ A2, const unsigned short* __restrict__ W0,
    const unsigned short* __restrict__ W1, const unsigned short* __restrict__ W2,
    const float* __restrict__ b0, const float* __restrict__ b1, const float* __restrict__ b2,
    unsigned short* __restrict__ O0, unsigned short* __restrict__ O1,
    unsigned short* __restrict__ O2) {
    const unsigned short* A;
    const unsigned short* W;
    const float* bias;
    unsigned short* O;
    if (blockIdx.z == 0) { A = A0; W = W0; bias = b0; O = O0; }
    else if (blockIdx.z == 1) { A = A1; W = W1; bias = b1; O = O1; }
    else { A = A2; W = W2; bias = b2; O = O2; }

    __shared__ __align__(16) unsigned short Asm[128 * 32];
    __shared__ __align__(16) unsigned short Bsm[128 * 32];

    const int t = threadIdx.x;
    const int w = t >> 6, l = t & 63;
    const int quad = l >> 4, lr = l & 15;
    const int wm = w >> 1, wn = w & 1;
    const int m0 = blockIdx.y * 128, n0 = blockIdx.x * 128;

    f32x4 zero = {0.f, 0.f, 0.f, 0.f};
    f32x4 acc[4][4];
#pragma unroll
    for (int i = 0; i < 4; i++)
#pragma unroll
        for (int j = 0; j < 4; j++) acc[i][j] = zero;

    const int c0 = w * 2, c1 = w * 2 + 1;
    const int ar0 = c0 * 16 + (l >> 2), ar1 = c1 * 16 + (l >> 2);
    const int acol = (l & 3) * 8;

    for (int kt = 0; kt < D_DIM / 32; ++kt) {
        const int k0 = kt * 32;
        __syncthreads();
        __builtin_amdgcn_global_load_lds(
            (const __attribute__((address_space(1))) void*)(A + (size_t)(m0 + ar0) * D_DIM + k0 + acol),
            (__attribute__((address_space(3))) void*)(&Asm[c0 * 512]), 16, 0, 0);
        __builtin_amdgcn_global_load_lds(
            (const __attribute__((address_space(1))) void*)(A + (size_t)(m0 + ar1) * D_DIM + k0 + acol),
            (__attribute__((address_space(3))) void*)(&Asm[c1 * 512]), 16, 0, 0);
        __builtin_amdgcn_global_load_lds(
            (const __attribute__((address_space(1))) void*)(W + (size_t)(n0 + ar0) * D_DIM + k0 + acol),
            (__attribute__((address_space(3))) void*)(&Bsm[c0 * 512]), 16, 0, 0);
        __builtin_amdgcn_global_load_lds(
            (const __attribute__((address_space(1))) void*)(W + (size_t)(n0 + ar1) * D_DIM + k0 + acol),
            (__attribute__((address_space(3))) void*)(&Bsm[c1 * 512]), 16, 0, 0);
        __syncthreads();

        short8 af[4], bf[4];
#pragma unroll
        for (int i = 0; i < 4; i++)
            af[i] = *(const short8*)&Asm[(wm * 64 + i * 16 + lr) * 32 + quad * 8];
#pragma unroll
        for (int j = 0; j < 4; j++)
            bf[j] = *(const short8*)&Bsm[(wn * 64 + j * 16 + lr) * 32 + quad * 8];
#pragma unroll
        for (int i = 0; i < 4; i++)
#pragma unroll
            for (int j = 0; j < 4; j++)
                acc[i][j] = __builtin_amdgcn_mfma_f32_16x16x32_bf16(af[i], bf[j], acc[i][j], 0, 0, 0);
    }

#pragma unroll
    for (int j = 0; j < 4; j++) {
        const int gn = n0 + wn * 64 + j * 16 + lr;
        const float bj = bias[gn];
#pragma unroll
        for (int i = 0; i < 4; i++) {
            const int gmb = m0 + wm * 64 + i * 16 + quad * 4;
#pragma unroll
            for (int r = 0; r < 4; r++) {
                float v = acc[i][j][r] + bj;
                v = fmaxf(v, 0.f);
                O[(size_t)(gmb + r) * D_DIM + gn] = f2bf(v);
            }
        }
    }
}

// ---------------- V transpose: (B,S,D) bf16 -> (B,H,dh,S) bf16 ----------------
__global__ __launch_bounds__(256) void transpose_v(const unsigned short* __restrict__ Vb,
                                                   unsigned short* __restrict__ Vt) {
    __shared__ unsigned short tile[64][65];
    const int s0 = blockIdx.x * 64, h = blockIdx.y, b = blockIdx.z;
    const int t = threadIdx.x;
#pragma unroll
    for (int p = 0; p < 16; p++) {
        int idx = p * 256 + t;
        int si = idx >> 6, ni = idx & 63;
        tile[si][ni] = Vb[(size_t)(b * S_LEN + s0 + si) * D_DIM + h * DH + ni];
    }
    __syncthreads();
#pragma unroll
    for (int p = 0; p < 16; p++) {
        int idx = p * 256 + t;
        int ni = idx >> 6, si = idx & 63;
        Vt[((size_t)(b * NHEAD + h) * DH + ni) * S_LEN + s0 + si] = tile[si][ni];
    }
}

// ---------------- flash attention: no-max softmax (scores provably bounded) ----------------
// grid (S/64, H, B), block 256 = 4 waves; wave = 16 q-rows; 64-key double-buffered LDS tiles.
// K/V: XOR-swizzled 16B chunks: chunk(key,cb) at key*8 + (cb^(key&7)).
// P: per-wave bf16 16x64, XOR-swizzled 16B chunks within rows. LDS total = 40960 B = 4 blk/CU.
__global__ __launch_bounds__(256) void attn_kernel(const unsigned short* __restrict__ Qb,
                                                   const unsigned short* __restrict__ Kb,
                                                   const unsigned short* __restrict__ Vt,
                                                   const float* __restrict__ qmask,
                                                   const float* __restrict__ km_pen,
                                                   unsigned short* __restrict__ Oout) {
    __shared__ __align__(16) unsigned short Ks[2][64 * 64];
    __shared__ __align__(16) unsigned short Vs[2][64 * 64];
    __shared__ __align__(16) unsigned short Ps[4][16 * 64];

    const int w = threadIdx.x >> 6, l = threadIdx.x & 63;
    const int quad = l >> 4, lr = l & 15;
    const int q0 = blockIdx.x * 64, h = blockIdx.y, b = blockIdx.z;
    const int qbase = q0 + w * 16;
    const float NEGF = -4294967295.0f;
    const float scale = 0.125f;  // 1/sqrt(64)

    const int cA = w * 128 + l;
    const int cB = w * 128 + 64 + l;
    const int keyA = cA >> 3, cbA = (cA & 7) ^ (keyA & 7);
    const int keyB = cB >> 3, cbB = (cB & 7) ^ (keyB & 7);
    const unsigned short* Krow = Kb + (size_t)b * S_LEN * D_DIM + h * DH;
    const unsigned short* Vrow = Vt + (size_t)(b * NHEAD + h) * DH * S_LEN;

    const unsigned short* qptr = Qb + (size_t)(b * S_LEN + qbase + lr) * D_DIM + h * DH + quad * 8;
    const short8 qf0 = *(const short8*)(qptr);
    const short8 qf1 = *(const short8*)(qptr + 32);

    f32x4 zero = {0.f, 0.f, 0.f, 0.f};
    f32x4 o[4];
#pragma unroll
    for (int j = 0; j < 4; j++) o[j] = zero;
    float l_part[4] = {0.f, 0.f, 0.f, 0.f};

    unsigned short* myP = Ps[w];
    const int swz0 = quad ^ (lr & 7);
    const int swz1 = (quad + 4) ^ (lr & 7);
    const int ntiles = q0 / 64 + 1;

    auto stage = [&](int k0, int bufIdx) {
        __builtin_amdgcn_global_load_lds(
            (const __attribute__((address_space(1))) void*)(Krow + (size_t)(k0 + keyA) * D_DIM + cbA * 8),
            (__attribute__((address_space(3))) void*)(&Ks[bufIdx][(w * 128) * 8]), 16, 0, 0);
        __builtin_amdgcn_global_load_lds(
            (const __attribute__((address_space(1))) void*)(Krow + (size_t)(k0 + keyB) * D_DIM + cbB * 8),
            (__attribute__((address_space(3))) void*)(&Ks[bufIdx][(w * 128 + 64) * 8]), 16, 0, 0);
        __builtin_amdgcn_global_load_lds(
            (const __attribute__((address_space(1))) void*)(Vrow + (size_t)keyA * S_LEN + k0 + cbA * 8),
            (__attribute__((address_space(3))) void*)(&Vs[bufIdx][(w * 128) * 8]), 16, 0, 0);
        __builtin_amdgcn_global_load_lds(
            (const __attribute__((address_space(1))) void*)(Vrow + (size_t)keyB * S_LEN + k0 + cbB * 8),
            (__attribute__((address_space(3))) void*)(&Vs[bufIdx][(w * 128 + 64) * 8]), 16, 0, 0);
    };

    stage(0, 0);
    __syncthreads();

    for (int kt = 0; kt < ntiles; ++kt) {
        const int k0 = kt * 64;
        const int cur = kt & 1;
        if (kt + 1 < ntiles) stage(k0 + 64, cur ^ 1);

        float kmv[4];
#pragma unroll
        for (int nf = 0; nf < 4; nf++) kmv[nf] = km_pen[b * S_LEN + k0 + nf * 16 + lr];

        // ---- scores: 16q x 64k ----
        f32x4 sc[4];
#pragma unroll
        for (int nf = 0; nf < 4; nf++) {
            const int key = nf * 16 + lr;
            const short8 kf0 = *(const short8*)&Ks[cur][(key * 8 + swz0) * 8];
            const short8 kf1 = *(const short8*)&Ks[cur][(key * 8 + swz1) * 8];
            f32x4 z = zero;
            z = __builtin_amdgcn_mfma_f32_16x16x32_bf16(qf0, kf0, z, 0, 0, 0);
            z = __builtin_amdgcn_mfma_f32_16x16x32_bf16(qf1, kf1, z, 0, 0, 0);
            sc[nf] = z;
        }

        // ---- V fragments (independent of P; hoisted above softmax) ----
        short8 vf[2][4];
#pragma unroll
        for (int s = 0; s < 2; s++) {
            const int swz = s ? swz1 : swz0;
#pragma unroll
            for (int j = 0; j < 4; j++)
                vf[s][j] = *(const short8*)&Vs[cur][((j * 16 + lr) * 8 + swz) * 8];
        }

        // ---- softmax: direct exp, no max subtraction (scores bounded ~5) ----
#pragma unroll
        for (int r = 0; r < 4; r++) {
            const int row = quad * 4 + r;
            const int q = qbase + row;
            const float v0 = (k0 + lr <= q) ? sc[0][r] * scale + kmv[0] : NEGF;
            const float v1 = (k0 + 16 + lr <= q) ? sc[1][r] * scale + kmv[1] : NEGF;
            const float v2 = (k0 + 32 + lr <= q) ? sc[2][r] * scale + kmv[2] : NEGF;
            const float v3 = (k0 + 48 + lr <= q) ? sc[3][r] * scale + kmv[3] : NEGF;
            const float e0 = __expf(v0);
            const float e1 = __expf(v1);
            const float e2 = __expf(v2);
            const float e3 = __expf(v3);
            l_part[r] += (e0 + e1) + (e2 + e3);
            // P^bf16 write, XOR-swizzled chunks: idx = row*64 + ((col>>3 ^ row&7)<<3) + (col&7)
            const int rb = (row & 7);
            const int base = row * 64 + (lr & 7);
            myP[base + ((((0 * 2) + (lr >> 3)) ^ rb) << 3)] = f2bf(e0);
            myP[base + ((((1 * 2) + (lr >> 3)) ^ rb) << 3)] = f2bf(e1);
            myP[base + ((((2 * 2) + (lr >> 3)) ^ rb) << 3)] = f2bf(e2);
            myP[base + ((((3 * 2) + (lr >> 3)) ^ rb) << 3)] = f2bf(e3);
        }

        // ---- P (A-layout read) + PV ----
#pragma unroll
        for (int s = 0; s < 2; s++) {
            const short8 pf = *(const short8*)&myP[lr * 64 + (((s * 4 + quad) ^ (lr & 7)) << 3)];
#pragma unroll
            for (int j = 0; j < 4; j++)
                o[j] = __builtin_amdgcn_mfma_f32_16x16x32_bf16(pf, vf[s][j], o[j], 0, 0, 0);
        }
        __syncthreads();
    }

    // ---- deferred denominator reduction + store ----
#pragma unroll
    for (int r = 0; r < 4; r++) {
        float ls = l_part[r];
        ls += __shfl_xor(ls, 1);
        ls += __shfl_xor(ls, 2);
        ls += __shfl_xor(ls, 4);
        ls += __shfl_xor(ls, 8);
        const int q = qbase + quad * 4 + r;
        const float qm = qmask[b * S_LEN + q];
        const float inv = (ls > 0.f) ? qm / ls : 0.f;
#pragma unroll
        for (int j = 0; j < 4; j++) {
            Oout[(size_t)(b * S_LEN + q) * D_DIM + h * DH + j * 16 + lr] = f2bf(o[j][r] * inv);
        }
    }
}

// ---------------- residual + layernorm (ddof=1, /(std+eps)) ----------------
__global__ __launch_bounds__(256) void ln_kernel(const unsigned short* __restrict__ attn,
                                                 const float* __restrict__ queries,
                                                 const float* __restrict__ gamma,
                                                 const float* __restrict__ beta,
                                                 float* __restrict__ out) {
    const int row = blockIdx.x;
    const int t = threadIdx.x;
    const ushort4 ab = ((const ushort4*)(attn + (size_t)row * D_DIM))[t];
    const float4 qv = ((const float4*)(queries + (size_t)row * D_DIM))[t];
    float4 x;
    x.x = bf2f(ab.x) + qv.x; x.y = bf2f(ab.y) + qv.y;
    x.z = bf2f(ab.z) + qv.z; x.w = bf2f(ab.w) + qv.w;
    float s = x.x + x.y + x.z + x.w;
    float sq = x.x * x.x + x.y * x.y + x.z * x.z + x.w * x.w;
    for (int o = 1; o < 64; o <<= 1) { s += __shfl_xor(s, o); sq += __shfl_xor(sq, o); }
    __shared__ float rs[4], rq[4];
    const int w = t >> 6;
    if ((t & 63) == 0) { rs[w] = s; rq[w] = sq; }
    __syncthreads();
    s = rs[0] + rs[1] + rs[2] + rs[3];
    sq = rq[0] + rq[1] + rq[2] + rq[3];
    const float mean = s * (1.0f / 1024.0f);
    float var = (sq - s * mean) * (1.0f / 1023.0f);
    var = fmaxf(var, 0.f);
    const float inv = 1.0f / (sqrtf(var) + 1e-8f);
    const float4 g = ((const float4*)gamma)[t];
    const float4 bb = ((const float4*)beta)[t];
    float4 y;
    y.x = g.x * (x.x - mean) * inv + bb.x;
    y.y = g.y * (x.y - mean) * inv + bb.y;
    y.z = g.z * (x.z - mean) * inv + bb.z;
    y.w = g.w * (x.w - mean) * inv + bb.w;
    ((float4*)(out + (size_t)row * D_DIM))[t] = y;
}

extern "C" void kernel_launch(void* const* d_in, const int* in_sizes, int n_in, void* d_out,
                              int out_size, void* d_ws, size_t ws_size, hipStream_t stream) {
    const float* queries = (const float*)d_in[0];
    const float* keys = (const float*)d_in[1];
    const float* values = (const float*)d_in[2];
    const float* Wq = (const float*)d_in[3];
    const float* bq = (const float*)d_in[4];
    const float* Wk = (const float*)d_in[5];
    const float* bk = (const float*)d_in[6];
    const float* Wv = (const float*)d_in[7];
    const float* bv = (const float*)d_in[8];
    const float* gamma = (const float*)d_in[9];
    const float* beta = (const float*)d_in[10];
    float* out = (float*)d_out;
    char* ws = (char*)d_ws;

    const size_t MB = 1048576;
    unsigned short* qin = (unsigned short*)(ws + 0);        // 8MB, dead after proj
    unsigned short* kin = (unsigned short*)(ws + 8 * MB);   // 8MB, dead after proj
    unsigned short* vin = (unsigned short*)(ws + 16 * MB);  // 8MB, dead after proj
    unsigned short* wqb = (unsigned short*)(ws + 24 * MB);  // 2MB
    unsigned short* wkb = (unsigned short*)(ws + 26 * MB);  // 2MB
    unsigned short* wvb = (unsigned short*)(ws + 28 * MB);  // 2MB
    unsigned short* Qb = (unsigned short*)(ws + 30 * MB);   // 8MB
    unsigned short* Kb = (unsigned short*)(ws + 38 * MB);   // 8MB
    unsigned short* Vb = (unsigned short*)(ws + 46 * MB);   // 8MB
    unsigned short* Vt = (unsigned short*)(ws + 0);         // aliases qin (dead by then)
    unsigned short* attn_o = (unsigned short*)(ws + 8 * MB);  // 8MB bf16, aliases kin (dead)
    float* qm = (float*)(ws + 54 * MB);
    float* km = (float*)(ws + 54 * MB + 16384);

    const int n4_w = D_DIM * D_DIM / 4;  // 262144

    cvt3_mask_kernel<<<dim3(NROWS, 3), 256, 0, stream>>>(queries, keys, values, qin, kin, vin,
                                                         qm, km);
    cvt3_kernel<<<dim3(n4_w / 256, 3), 256, 0, stream>>>(Wq, Wk, Wv, wqb, wkb, wvb, n4_w);

    proj_kernel<<<dim3(D_DIM / 128, NROWS / 128, 3), 256, 0, stream>>>(
        qin, kin, vin, wqb, wkb, wvb, bq, bk, bv, Qb, Kb, Vb);

    transpose_v<<<dim3(S_LEN / 64, NHEAD, BATCH), 256, 0, stream>>>(Vb, Vt);

    attn_kernel<<<dim3(S_LEN / 64, NHEAD, BATCH), 256, 0, stream>>>(Qb, Kb, Vt, qm, km, attn_o);

    ln_kernel<<<NROWS, 256, 0, stream>>>(attn_o, queries, gamma, beta, out);
}

// Round 4
// 222.600 us; speedup vs baseline: 1.8945x; 1.1171x over previous
//
#include <hip/hip_runtime.h>

#define S_LEN 2048
#define D_DIM 1024
#define NHEAD 16
#define DH 64
#define BATCH 2
#define NROWS (BATCH * S_LEN)  // 4096

typedef __attribute__((ext_vector_type(8))) short short8;
typedef __attribute__((ext_vector_type(4))) float f32x4;

static __device__ __forceinline__ unsigned short f2bf(float f) {
    unsigned int u = __builtin_bit_cast(unsigned int, f);
    u += 0x7fffu + ((u >> 16) & 1u);
    return (unsigned short)(u >> 16);
}
static __device__ __forceinline__ float bf2f(unsigned short h) {
    unsigned int u = ((unsigned int)h) << 16;
    return __builtin_bit_cast(float, u);
}
static __device__ __forceinline__ unsigned short f2bf_trunc(float f) {
    return (unsigned short)(__builtin_bit_cast(unsigned int, f) >> 16);
}

// ---------------- fp32 -> bf16 convert for q/k/v + fused padding masks ----------------
__global__ __launch_bounds__(256) void cvt3_mask_kernel(
    const float* __restrict__ s0, const float* __restrict__ s1, const float* __restrict__ s2,
    unsigned short* __restrict__ d0, unsigned short* __restrict__ d1,
    unsigned short* __restrict__ d2, float* __restrict__ qm, float* __restrict__ km) {
    const int y = blockIdx.y;
    const float* src = y == 0 ? s0 : (y == 1 ? s1 : s2);
    unsigned short* dst = y == 0 ? d0 : (y == 1 ? d1 : d2);
    const int row = blockIdx.x;
    const int t = threadIdx.x;
    const size_t i = (size_t)row * 256 + t;
    float4 v = ((const float4*)src)[i];
    ushort4 o;
    o.x = f2bf(v.x); o.y = f2bf(v.y); o.z = f2bf(v.z); o.w = f2bf(v.w);
    ((ushort4*)dst)[i] = o;
    if (y < 2) {
        float s = v.x + v.y + v.z + v.w;
        for (int off = 1; off < 64; off <<= 1) s += __shfl_xor(s, off);
        __shared__ float red[4];
        const int w = t >> 6;
        if ((t & 63) == 0) red[w] = s;
        __syncthreads();
        if (t == 0) {
            float tt = red[0] + red[1] + red[2] + red[3];
            if (y == 0)
                qm[row] = (tt != 0.0f) ? 1.0f : 0.0f;
            else
                km[row] = (tt != 0.0f) ? 0.0f : -4294967295.0f;
        }
    }
}

// ---------------- fp32 -> bf16 convert, 3 tensors (weights) ----------------
__global__ __launch_bounds__(256) void cvt3_kernel(const float* __restrict__ s0,
                                                   const float* __restrict__ s1,
                                                   const float* __restrict__ s2,
                                                   unsigned short* __restrict__ d0,
                                                   unsigned short* __restrict__ d1,
                                                   unsigned short* __restrict__ d2, int n4) {
    const float* src = blockIdx.y == 0 ? s0 : (blockIdx.y == 1 ? s1 : s2);
    unsigned short* dst = blockIdx.y == 0 ? d0 : (blockIdx.y == 1 ? d1 : d2);
    int i = blockIdx.x * 256 + threadIdx.x;
    if (i < n4) {
        float4 v = ((const float4*)src)[i];
        ushort4 o;
        o.x = f2bf(v.x); o.y = f2bf(v.y); o.z = f2bf(v.z); o.w = f2bf(v.w);
        ((ushort4*)dst)[i] = o;
    }
}

// ---------------- fused QKV projection: O = relu(A @ W^T + b), bf16 MFMA ----------------
// z==0 (Q): output scaled by 1/sqrt(dh)=0.125 (folded attention scale).
// z==2 (V): output written DIRECTLY in (B,H,dh,S) transposed layout (Vt).
__global__ __launch_bounds__(256) void proj_kernel(
    const unsigned short* __restrict__ A0, const unsigned short* __restrict__ A1,
    const unsigned short* __restrict__ A2, const unsigned short* __restrict__ W0,
    const unsigned short* __restrict__ W1, const unsigned short* __restrict__ W2,
    const float* __restrict__ b0, const float* __restrict__ b1, const float* __restrict__ b2,
    unsigned short* __restrict__ O0, unsigned short* __restrict__ O1,
    unsigned short* __restrict__ O2) {
    const unsigned short* A;
    const unsigned short* W;
    const float* bias;
    unsigned short* O;
    if (blockIdx.z == 0) { A = A0; W = W0; bias = b0; O = O0; }
    else if (blockIdx.z == 1) { A = A1; W = W1; bias = b1; O = O1; }
    else { A = A2; W = W2; bias = b2; O = O2; }

    __shared__ __align__(16) unsigned short Asm[128 * 32];
    __shared__ __align__(16) unsigned short Bsm[128 * 32];

    const int t = threadIdx.x;
    const int w = t >> 6, l = t & 63;
    const int quad = l >> 4, lr = l & 15;
    const int wm = w >> 1, wn = w & 1;
    const int m0 = blockIdx.y * 128, n0 = blockIdx.x * 128;

    f32x4 zero = {0.f, 0.f, 0.f, 0.f};
    f32x4 acc[4][4];
#pragma unroll
    for (int i = 0; i < 4; i++)
#pragma unroll
        for (int j = 0; j < 4; j++) acc[i][j] = zero;

    const int c0 = w * 2, c1 = w * 2 + 1;
    const int ar0 = c0 * 16 + (l >> 2), ar1 = c1 * 16 + (l >> 2);
    const int acol = (l & 3) * 8;

    for (int kt = 0; kt < D_DIM / 32; ++kt) {
        const int k0 = kt * 32;
        __syncthreads();
        __builtin_amdgcn_global_load_lds(
            (const __attribute__((address_space(1))) void*)(A + (size_t)(m0 + ar0) * D_DIM + k0 + acol),
            (__attribute__((address_space(3))) void*)(&Asm[c0 * 512]), 16, 0, 0);
        __builtin_amdgcn_global_load_lds(
            (const __attribute__((address_space(1))) void*)(A + (size_t)(m0 + ar1) * D_DIM + k0 + acol),
            (__attribute__((address_space(3))) void*)(&Asm[c1 * 512]), 16, 0, 0);
        __builtin_amdgcn_global_load_lds(
            (const __attribute__((address_space(1))) void*)(W + (size_t)(n0 + ar0) * D_DIM + k0 + acol),
            (__attribute__((address_space(3))) void*)(&Bsm[c0 * 512]), 16, 0, 0);
        __builtin_amdgcn_global_load_lds(
            (const __attribute__((address_space(1))) void*)(W + (size_t)(n0 + ar1) * D_DIM + k0 + acol),
            (__attribute__((address_space(3))) void*)(&Bsm[c1 * 512]), 16, 0, 0);
        __syncthreads();

        short8 af[4], bf[4];
#pragma unroll
        for (int i = 0; i < 4; i++)
            af[i] = *(const short8*)&Asm[(wm * 64 + i * 16 + lr) * 32 + quad * 8];
#pragma unroll
        for (int j = 0; j < 4; j++)
            bf[j] = *(const short8*)&Bsm[(wn * 64 + j * 16 + lr) * 32 + quad * 8];
#pragma unroll
        for (int i = 0; i < 4; i++)
#pragma unroll
            for (int j = 0; j < 4; j++)
                acc[i][j] = __builtin_amdgcn_mfma_f32_16x16x32_bf16(af[i], bf[j], acc[i][j], 0, 0, 0);
    }

    const float oscale = (blockIdx.z == 0) ? 0.125f : 1.0f;
    const bool vt_layout = (blockIdx.z == 2);
#pragma unroll
    for (int j = 0; j < 4; j++) {
        const int gn = n0 + wn * 64 + j * 16 + lr;
        const float bj = bias[gn];
#pragma unroll
        for (int i = 0; i < 4; i++) {
            const int gmb = m0 + wm * 64 + i * 16 + quad * 4;
#pragma unroll
            for (int r = 0; r < 4; r++) {
                float v = fmaxf(acc[i][j][r] + bj, 0.f) * oscale;
                if (vt_layout) {
                    const int m = gmb + r;
                    const int bb = m >> 11, s = m & 2047;
                    const int hh = gn >> 6, dd = gn & 63;
                    O[((size_t)((bb * NHEAD + hh) * DH + dd)) * S_LEN + s] = f2bf(v);
                } else {
                    O[(size_t)(gmb + r) * D_DIM + gn] = f2bf(v);
                }
            }
        }
    }
}

// ---------------- flash attention: no-max softmax + split-K balancing ----------------
// grid (48, H, B). x<32: split blocks for q-tiles 31..16 (two balanced key-halves each,
// fp32 partials). x>=32: full blocks for q-tiles 15..0 (final bf16). Causal mask peeled
// to the diagonal tile only. Q pre-scaled by 0.125 at projection.
__global__ __launch_bounds__(256) void attn_kernel(
    const unsigned short* __restrict__ Qb, const unsigned short* __restrict__ Kb,
    const unsigned short* __restrict__ Vt, const float* __restrict__ qmask,
    const float* __restrict__ km_pen, unsigned short* __restrict__ Oout,
    float* __restrict__ oP0, float* __restrict__ oP1, float* __restrict__ lP) {
    __shared__ __align__(16) unsigned short Ks[2][64 * 64];
    __shared__ __align__(16) unsigned short Vs[2][64 * 64];
    __shared__ __align__(16) unsigned short Ps[4][16 * 64];

    const int w = threadIdx.x >> 6, l = threadIdx.x & 63;
    const int quad = l >> 4, lr = l & 15;
    const int h = blockIdx.y, b = blockIdx.z;
    const float NEGF = -4294967295.0f;

    // ---- work assignment (LPT-ish: longest first) ----
    int qt, lo, hi, sp;
    bool full;
    const int x = blockIdx.x;
    if (x < 32) {
        qt = 31 - (x >> 1);
        sp = x & 1;
        full = false;
        const int n0 = (qt + 2) >> 1;
        if (sp == 0) { lo = 0; hi = n0; }
        else { lo = n0; hi = qt + 1; }
    } else {
        qt = 47 - x;
        sp = 0;
        full = true;
        lo = 0;
        hi = qt + 1;
    }
    const int q0 = qt * 64;
    const int qbase = q0 + w * 16;

    const int cA = w * 128 + l;
    const int cB = w * 128 + 64 + l;
    const int keyA = cA >> 3, cbA = (cA & 7) ^ (keyA & 7);
    const int keyB = cB >> 3, cbB = (cB & 7) ^ (keyB & 7);
    const unsigned short* Krow = Kb + (size_t)b * S_LEN * D_DIM + h * DH;
    const unsigned short* Vrow = Vt + (size_t)(b * NHEAD + h) * DH * S_LEN;

    const unsigned short* qptr = Qb + (size_t)(b * S_LEN + qbase + lr) * D_DIM + h * DH + quad * 8;
    const short8 qf0 = *(const short8*)(qptr);
    const short8 qf1 = *(const short8*)(qptr + 32);

    f32x4 zero = {0.f, 0.f, 0.f, 0.f};
    f32x4 o[4];
#pragma unroll
    for (int j = 0; j < 4; j++) o[j] = zero;
    float l_part[4] = {0.f, 0.f, 0.f, 0.f};

    unsigned short* myP = Ps[w];
    const int swz0 = quad ^ (lr & 7);
    const int swz1 = (quad + 4) ^ (lr & 7);

    auto stage = [&](int k0, int bufIdx) {
        __builtin_amdgcn_global_load_lds(
            (const __attribute__((address_space(1))) void*)(Krow + (size_t)(k0 + keyA) * D_DIM + cbA * 8),
            (__attribute__((address_space(3))) void*)(&Ks[bufIdx][(w * 128) * 8]), 16, 0, 0);
        __builtin_amdgcn_global_load_lds(
            (const __attribute__((address_space(1))) void*)(Krow + (size_t)(k0 + keyB) * D_DIM + cbB * 8),
            (__attribute__((address_space(3))) void*)(&Ks[bufIdx][(w * 128 + 64) * 8]), 16, 0, 0);
        __builtin_amdgcn_global_load_lds(
            (const __attribute__((address_space(1))) void*)(Vrow + (size_t)keyA * S_LEN + k0 + cbA * 8),
            (__attribute__((address_space(3))) void*)(&Vs[bufIdx][(w * 128) * 8]), 16, 0, 0);
        __builtin_amdgcn_global_load_lds(
            (const __attribute__((address_space(1))) void*)(Vrow + (size_t)keyB * S_LEN + k0 + cbB * 8),
            (__attribute__((address_space(3))) void*)(&Vs[bufIdx][(w * 128 + 64) * 8]), 16, 0, 0);
    };

    stage(lo * 64, 0);
    __syncthreads();

    for (int kt = lo; kt < hi; ++kt) {
        const int k0 = kt * 64;
        const int cur = (kt - lo) & 1;
        if (kt + 1 < hi) stage((kt + 1) * 64, cur ^ 1);

        float kmv[4];
#pragma unroll
        for (int nf = 0; nf < 4; nf++) kmv[nf] = km_pen[b * S_LEN + k0 + nf * 16 + lr];

        // ---- scores: 16q x 64k (Q pre-scaled) ----
        f32x4 sc[4];
#pragma unroll
        for (int nf = 0; nf < 4; nf++) {
            const int key = nf * 16 + lr;
            const short8 kf0 = *(const short8*)&Ks[cur][(key * 8 + swz0) * 8];
            const short8 kf1 = *(const short8*)&Ks[cur][(key * 8 + swz1) * 8];
            f32x4 z = zero;
            z = __builtin_amdgcn_mfma_f32_16x16x32_bf16(qf0, kf0, z, 0, 0, 0);
            z = __builtin_amdgcn_mfma_f32_16x16x32_bf16(qf1, kf1, z, 0, 0, 0);
            sc[nf] = z;
        }

        // ---- V fragments (independent of P) ----
        short8 vf[2][4];
#pragma unroll
        for (int s = 0; s < 2; s++) {
            const int swz = s ? swz1 : swz0;
#pragma unroll
            for (int j = 0; j < 4; j++)
                vf[s][j] = *(const short8*)&Vs[cur][((j * 16 + lr) * 8 + swz) * 8];
        }

        // ---- softmax: direct exp (bounded scores); causal only on diagonal tile ----
        if (kt == qt) {
#pragma unroll
            for (int r = 0; r < 4; r++) {
                const int row = quad * 4 + r;
                const int q = qbase + row;
                const float v0 = (k0 + lr <= q) ? sc[0][r] + kmv[0] : NEGF;
                const float v1 = (k0 + 16 + lr <= q) ? sc[1][r] + kmv[1] : NEGF;
                const float v2 = (k0 + 32 + lr <= q) ? sc[2][r] + kmv[2] : NEGF;
                const float v3 = (k0 + 48 + lr <= q) ? sc[3][r] + kmv[3] : NEGF;
                const float e0 = __expf(v0);
                const float e1 = __expf(v1);
                const float e2 = __expf(v2);
                const float e3 = __expf(v3);
                l_part[r] += (e0 + e1) + (e2 + e3);
                const int rb = (row & 7);
                const int base = row * 64 + (lr & 7);
                myP[base + (((0 + (lr >> 3)) ^ rb) << 3)] = f2bf_trunc(e0);
                myP[base + (((2 + (lr >> 3)) ^ rb) << 3)] = f2bf_trunc(e1);
                myP[base + (((4 + (lr >> 3)) ^ rb) << 3)] = f2bf_trunc(e2);
                myP[base + (((6 + (lr >> 3)) ^ rb) << 3)] = f2bf_trunc(e3);
            }
        } else {
#pragma unroll
            for (int r = 0; r < 4; r++) {
                const int row = quad * 4 + r;
                const float e0 = __expf(sc[0][r] + kmv[0]);
                const float e1 = __expf(sc[1][r] + kmv[1]);
                const float e2 = __expf(sc[2][r] + kmv[2]);
                const float e3 = __expf(sc[3][r] + kmv[3]);
                l_part[r] += (e0 + e1) + (e2 + e3);
                const int rb = (row & 7);
                const int base = row * 64 + (lr & 7);
                myP[base + (((0 + (lr >> 3)) ^ rb) << 3)] = f2bf_trunc(e0);
                myP[base + (((2 + (lr >> 3)) ^ rb) << 3)] = f2bf_trunc(e1);
                myP[base + (((4 + (lr >> 3)) ^ rb) << 3)] = f2bf_trunc(e2);
                myP[base + (((6 + (lr >> 3)) ^ rb) << 3)] = f2bf_trunc(e3);
            }
        }

        // ---- P (A-layout read) + PV ----
#pragma unroll
        for (int s = 0; s < 2; s++) {
            const short8 pf = *(const short8*)&myP[lr * 64 + (((s * 4 + quad) ^ (lr & 7)) << 3)];
#pragma unroll
            for (int j = 0; j < 4; j++)
                o[j] = __builtin_amdgcn_mfma_f32_16x16x32_bf16(pf, vf[s][j], o[j], 0, 0, 0);
        }
        __syncthreads();
    }

    // ---- epilogue ----
    if (full) {
#pragma unroll
        for (int r = 0; r < 4; r++) {
            float ls = l_part[r];
            ls += __shfl_xor(ls, 1);
            ls += __shfl_xor(ls, 2);
            ls += __shfl_xor(ls, 4);
            ls += __shfl_xor(ls, 8);
            const int q = qbase + quad * 4 + r;
            const float qm = qmask[b * S_LEN + q];
            const float inv = (ls > 0.f) ? qm / ls : 0.f;
#pragma unroll
            for (int j = 0; j < 4; j++) {
                Oout[(size_t)(b * S_LEN + q) * D_DIM + h * DH + j * 16 + lr] =
                    f2bf(o[j][r] * inv);
            }
        }
    } else {
        float* oP = sp ? oP1 : oP0;
#pragma unroll
        for (int r = 0; r < 4; r++) {
            float ls = l_part[r];
            ls += __shfl_xor(ls, 1);
            ls += __shfl_xor(ls, 2);
            ls += __shfl_xor(ls, 4);
            ls += __shfl_xor(ls, 8);
            const int q = qbase + quad * 4 + r;
            const int qr = q - 1024;  // q-tiles >= 16 only
            if (lr == 0) lP[sp * 32768 + (b * NHEAD + h) * 1024 + qr] = ls;
#pragma unroll
            for (int j = 0; j < 4; j++) {
                oP[(size_t)(b * 1024 + qr) * D_DIM + h * DH + j * 16 + lr] = o[j][r];
            }
        }
    }
}

// ---------------- residual + layernorm + split-K combine ----------------
__global__ __launch_bounds__(256) void ln_kernel(
    const unsigned short* __restrict__ attn, const float* __restrict__ oP0,
    const float* __restrict__ oP1, const float* __restrict__ lP,
    const float* __restrict__ qmask, const float* __restrict__ queries,
    const float* __restrict__ gamma, const float* __restrict__ beta,
    float* __restrict__ out) {
    const int row = blockIdx.x;
    const int t = threadIdx.x;
    const int b = row >> 11, q = row & 2047;
    const float4 qv = ((const float4*)(queries + (size_t)row * D_DIM))[t];
    float4 x;
    if (q < 1024) {
        const ushort4 ab = ((const ushort4*)(attn + (size_t)row * D_DIM))[t];
        x.x = bf2f(ab.x) + qv.x; x.y = bf2f(ab.y) + qv.y;
        x.z = bf2f(ab.z) + qv.z; x.w = bf2f(ab.w) + qv.w;
    } else {
        const int qr = q - 1024;
        const int h = t >> 4;  // (4t)/64
        const float ls = lP[(b * NHEAD + h) * 1024 + qr] +
                         lP[32768 + (b * NHEAD + h) * 1024 + qr];
        const float qmr = qmask[row];
        const float inv = (ls > 0.f) ? qmr / ls : 0.f;
        const size_t ri = (size_t)(b * 1024 + qr) * D_DIM;
        const float4 a0 = ((const float4*)(oP0 + ri))[t];
        const float4 a1 = ((const float4*)(oP1 + ri))[t];
        x.x = (a0.x + a1.x) * inv + qv.x;
        x.y = (a0.y + a1.y) * inv + qv.y;
        x.z = (a0.z + a1.z) * inv + qv.z;
        x.w = (a0.w + a1.w) * inv + qv.w;
    }
    float s = x.x + x.y + x.z + x.w;
    float sq = x.x * x.x + x.y * x.y + x.z * x.z + x.w * x.w;
    for (int o = 1; o < 64; o <<= 1) { s += __shfl_xor(s, o); sq += __shfl_xor(sq, o); }
    __shared__ float rs[4], rq[4];
    const int w = t >> 6;
    if ((t & 63) == 0) { rs[w] = s; rq[w] = sq; }
    __syncthreads();
    s = rs[0] + rs[1] + rs[2] + rs[3];
    sq = rq[0] + rq[1] + rq[2] + rq[3];
    const float mean = s * (1.0f / 1024.0f);
    float var = (sq - s * mean) * (1.0f / 1023.0f);
    var = fmaxf(var, 0.f);
    const float inv = 1.0f / (sqrtf(var) + 1e-8f);
    const float4 g = ((const float4*)gamma)[t];
    const float4 bb = ((const float4*)beta)[t];
    float4 y;
    y.x = g.x * (x.x - mean) * inv + bb.x;
    y.y = g.y * (x.y - mean) * inv + bb.y;
    y.z = g.z * (x.z - mean) * inv + bb.z;
    y.w = g.w * (x.w - mean) * inv + bb.w;
    ((float4*)(out + (size_t)row * D_DIM))[t] = y;
}

extern "C" void kernel_launch(void* const* d_in, const int* in_sizes, int n_in, void* d_out,
                              int out_size, void* d_ws, size_t ws_size, hipStream_t stream) {
    const float* queries = (const float*)d_in[0];
    const float* keys = (const float*)d_in[1];
    const float* values = (const float*)d_in[2];
    const float* Wq = (const float*)d_in[3];
    const float* bq = (const float*)d_in[4];
    const float* Wk = (const float*)d_in[5];
    const float* bk = (const float*)d_in[6];
    const float* Wv = (const float*)d_in[7];
    const float* bv = (const float*)d_in[8];
    const float* gamma = (const float*)d_in[9];
    const float* beta = (const float*)d_in[10];
    float* out = (float*)d_out;
    char* ws = (char*)d_ws;

    const size_t MB = 1048576;
    unsigned short* qin = (unsigned short*)(ws + 0);        // dead after proj
    unsigned short* kin = (unsigned short*)(ws + 8 * MB);   // dead after proj
    unsigned short* vin = (unsigned short*)(ws + 16 * MB);  // dead after proj
    unsigned short* wqb = (unsigned short*)(ws + 24 * MB);
    unsigned short* wkb = (unsigned short*)(ws + 26 * MB);
    unsigned short* wvb = (unsigned short*)(ws + 28 * MB);
    unsigned short* Qb = (unsigned short*)(ws + 30 * MB);
    unsigned short* Kb = (unsigned short*)(ws + 38 * MB);
    unsigned short* Vt = (unsigned short*)(ws + 46 * MB);     // written by proj z==2
    float* oP0 = (float*)(ws + 0);                            // aliases qin (dead)
    unsigned short* attn_o = (unsigned short*)(ws + 8 * MB);  // aliases kin (dead)
    float* oP1 = (float*)(ws + 16 * MB);                      // aliases vin (dead)
    float* qm = (float*)(ws + 54 * MB);
    float* km = (float*)(ws + 54 * MB + 16384);
    float* lP = (float*)(ws + 54 * MB + 32768);  // 2 splits x 2 x 16 x 1024 fp32 = 256KB

    const int n4_w = D_DIM * D_DIM / 4;

    cvt3_mask_kernel<<<dim3(NROWS, 3), 256, 0, stream>>>(queries, keys, values, qin, kin, vin,
                                                         qm, km);
    cvt3_kernel<<<dim3(n4_w / 256, 3), 256, 0, stream>>>(Wq, Wk, Wv, wqb, wkb, wvb, n4_w);

    proj_kernel<<<dim3(D_DIM / 128, NROWS / 128, 3), 256, 0, stream>>>(
        qin, kin, vin, wqb, wkb, wvb, bq, bk, bv, Qb, Kb, Vt);

    attn_kernel<<<dim3(48, NHEAD, BATCH), 256, 0, stream>>>(Qb, Kb, Vt, qm, km, attn_o, oP0,
                                                            oP1, lP);

    ln_kernel<<<NROWS, 256, 0, stream>>>(attn_o, oP0, oP1, lP, qm, queries, gamma, beta, out);
}

// Round 5
// 215.436 us; speedup vs baseline: 1.9575x; 1.0333x over previous
//
#include <hip/hip_runtime.h>

#define S_LEN 2048
#define D_DIM 1024
#define NHEAD 16
#define DH 64
#define BATCH 2
#define NROWS (BATCH * S_LEN)  // 4096

typedef __attribute__((ext_vector_type(8))) short short8;
typedef __attribute__((ext_vector_type(4))) float f32x4;

static __device__ __forceinline__ unsigned short f2bf(float f) {
    unsigned int u = __builtin_bit_cast(unsigned int, f);
    u += 0x7fffu + ((u >> 16) & 1u);
    return (unsigned short)(u >> 16);
}
static __device__ __forceinline__ float bf2f(unsigned short h) {
    unsigned int u = ((unsigned int)h) << 16;
    return __builtin_bit_cast(float, u);
}
static __device__ __forceinline__ unsigned short f2bf_trunc(float f) {
    return (unsigned short)(__builtin_bit_cast(unsigned int, f) >> 16);
}

// ---------------- fp32 -> bf16 convert (inputs + weights) + fused padding masks --------
// grid (5120, 3): rows 0..4095 = q/k/v rows (row-sum masks for y<2); rows 4096..5119 =
// Wq/Wk/Wv rows (1024 rows x 1024 cols, same 256-thread x float4 geometry).
__global__ __launch_bounds__(256) void cvt_all_kernel(
    const float* __restrict__ s0, const float* __restrict__ s1, const float* __restrict__ s2,
    const float* __restrict__ w0, const float* __restrict__ w1, const float* __restrict__ w2,
    unsigned short* __restrict__ d0, unsigned short* __restrict__ d1,
    unsigned short* __restrict__ d2, unsigned short* __restrict__ e0,
    unsigned short* __restrict__ e1, unsigned short* __restrict__ e2,
    float* __restrict__ qm, float* __restrict__ km) {
    const int y = blockIdx.y;
    const int row = blockIdx.x;
    const int t = threadIdx.x;
    const float* src;
    unsigned short* dst;
    size_t i;
    if (row < NROWS) {
        src = y == 0 ? s0 : (y == 1 ? s1 : s2);
        dst = y == 0 ? d0 : (y == 1 ? d1 : d2);
        i = (size_t)row * 256 + t;
    } else {
        src = y == 0 ? w0 : (y == 1 ? w1 : w2);
        dst = y == 0 ? e0 : (y == 1 ? e1 : e2);
        i = (size_t)(row - NROWS) * 256 + t;
    }
    float4 v = ((const float4*)src)[i];
    ushort4 o;
    o.x = f2bf(v.x); o.y = f2bf(v.y); o.z = f2bf(v.z); o.w = f2bf(v.w);
    ((ushort4*)dst)[i] = o;
    if (row < NROWS && y < 2) {
        float s = v.x + v.y + v.z + v.w;
        for (int off = 1; off < 64; off <<= 1) s += __shfl_xor(s, off);
        __shared__ float red[4];
        const int w = t >> 6;
        if ((t & 63) == 0) red[w] = s;
        __syncthreads();
        if (t == 0) {
            float tt = red[0] + red[1] + red[2] + red[3];
            if (y == 0)
                qm[row] = (tt != 0.0f) ? 1.0f : 0.0f;
            else
                km[row] = (tt != 0.0f) ? 0.0f : -4294967295.0f;
        }
    }
}

// ---------------- fused QKV projection: O = relu(A @ W^T + b), bf16 MFMA ----------------
// z==0 (Q): output scaled by 1/sqrt(dh)=0.125. z==2 (V): written in (B,H,dh,S) layout.
__global__ __launch_bounds__(256) void proj_kernel(
    const unsigned short* __restrict__ A0, const unsigned short* __restrict__ A1,
    const unsigned short* __restrict__ A2, const unsigned short* __restrict__ W0,
    const unsigned short* __restrict__ W1, const unsigned short* __restrict__ W2,
    const float* __restrict__ b0, const float* __restrict__ b1, const float* __restrict__ b2,
    unsigned short* __restrict__ O0, unsigned short* __restrict__ O1,
    unsigned short* __restrict__ O2) {
    const unsigned short* A;
    const unsigned short* W;
    const float* bias;
    unsigned short* O;
    if (blockIdx.z == 0) { A = A0; W = W0; bias = b0; O = O0; }
    else if (blockIdx.z == 1) { A = A1; W = W1; bias = b1; O = O1; }
    else { A = A2; W = W2; bias = b2; O = O2; }

    __shared__ __align__(16) unsigned short Asm[128 * 32];
    __shared__ __align__(16) unsigned short Bsm[128 * 32];

    const int t = threadIdx.x;
    const int w = t >> 6, l = t & 63;
    const int quad = l >> 4, lr = l & 15;
    const int wm = w >> 1, wn = w & 1;
    const int m0 = blockIdx.y * 128, n0 = blockIdx.x * 128;

    f32x4 zero = {0.f, 0.f, 0.f, 0.f};
    f32x4 acc[4][4];
#pragma unroll
    for (int i = 0; i < 4; i++)
#pragma unroll
        for (int j = 0; j < 4; j++) acc[i][j] = zero;

    const int c0 = w * 2, c1 = w * 2 + 1;
    const int ar0 = c0 * 16 + (l >> 2), ar1 = c1 * 16 + (l >> 2);
    const int acol = (l & 3) * 8;

    for (int kt = 0; kt < D_DIM / 32; ++kt) {
        const int k0 = kt * 32;
        __syncthreads();
        __builtin_amdgcn_global_load_lds(
            (const __attribute__((address_space(1))) void*)(A + (size_t)(m0 + ar0) * D_DIM + k0 + acol),
            (__attribute__((address_space(3))) void*)(&Asm[c0 * 512]), 16, 0, 0);
        __builtin_amdgcn_global_load_lds(
            (const __attribute__((address_space(1))) void*)(A + (size_t)(m0 + ar1) * D_DIM + k0 + acol),
            (__attribute__((address_space(3))) void*)(&Asm[c1 * 512]), 16, 0, 0);
        __builtin_amdgcn_global_load_lds(
            (const __attribute__((address_space(1))) void*)(W + (size_t)(n0 + ar0) * D_DIM + k0 + acol),
            (__attribute__((address_space(3))) void*)(&Bsm[c0 * 512]), 16, 0, 0);
        __builtin_amdgcn_global_load_lds(
            (const __attribute__((address_space(1))) void*)(W + (size_t)(n0 + ar1) * D_DIM + k0 + acol),
            (__attribute__((address_space(3))) void*)(&Bsm[c1 * 512]), 16, 0, 0);
        __syncthreads();

        short8 af[4], bf[4];
#pragma unroll
        for (int i = 0; i < 4; i++)
            af[i] = *(const short8*)&Asm[(wm * 64 + i * 16 + lr) * 32 + quad * 8];
#pragma unroll
        for (int j = 0; j < 4; j++)
            bf[j] = *(const short8*)&Bsm[(wn * 64 + j * 16 + lr) * 32 + quad * 8];
#pragma unroll
        for (int i = 0; i < 4; i++)
#pragma unroll
            for (int j = 0; j < 4; j++)
                acc[i][j] = __builtin_amdgcn_mfma_f32_16x16x32_bf16(af[i], bf[j], acc[i][j], 0, 0, 0);
    }

    const float oscale = (blockIdx.z == 0) ? 0.125f : 1.0f;
    const bool vt_layout = (blockIdx.z == 2);
#pragma unroll
    for (int j = 0; j < 4; j++) {
        const int gn = n0 + wn * 64 + j * 16 + lr;
        const float bj = bias[gn];
#pragma unroll
        for (int i = 0; i < 4; i++) {
            const int gmb = m0 + wm * 64 + i * 16 + quad * 4;
#pragma unroll
            for (int r = 0; r < 4; r++) {
                float v = fmaxf(acc[i][j][r] + bj, 0.f) * oscale;
                if (vt_layout) {
                    const int m = gmb + r;
                    const int bb = m >> 11, s = m & 2047;
                    const int hh = gn >> 6, dd = gn & 63;
                    O[((size_t)((bb * NHEAD + hh) * DH + dd)) * S_LEN + s] = f2bf(v);
                } else {
                    O[(size_t)(gmb + r) * D_DIM + gn] = f2bf(v);
                }
            }
        }
    }
}

// ---------------- flash attention: no-max softmax + uniform <=11-tile split-K ----------
// grid (63, H, B). ns(qt)=ceil((qt+1)/11): 1 for qt 0..10, 2 for 11..21, 3 for 22..31.
// LPT order: x 0..29 -> 3-split (qt 31..22), 30..51 -> 2-split (qt 21..11),
// 52..62 -> single (qt 10..0). ALL blocks write bf16 O-partials + fp32 l-partials.
__global__ __launch_bounds__(256) void attn_kernel(
    const unsigned short* __restrict__ Qb, const unsigned short* __restrict__ Kb,
    const unsigned short* __restrict__ Vt, const float* __restrict__ km_pen,
    unsigned short* __restrict__ oP0, unsigned short* __restrict__ oP1,
    unsigned short* __restrict__ oP2, float* __restrict__ lP) {
    __shared__ __align__(16) unsigned short Ks[2][64 * 64];
    __shared__ __align__(16) unsigned short Vs[2][64 * 64];
    __shared__ __align__(16) unsigned short Ps[4][16 * 64];

    const int w = threadIdx.x >> 6, l = threadIdx.x & 63;
    const int quad = l >> 4, lr = l & 15;
    const int h = blockIdx.y, b = blockIdx.z;
    const float NEGF = -4294967295.0f;

    // ---- work assignment (LPT: longest first) ----
    int qt, sp;
    const int x = blockIdx.x;
    int ns;
    if (x < 30) { qt = 31 - x / 3; sp = x % 3; ns = 3; }
    else if (x < 52) { int y = x - 30; qt = 21 - y / 2; sp = y % 2; ns = 2; }
    else { qt = 62 - x; sp = 0; ns = 1; }
    const int T = qt + 1;
    const int lo = sp * T / ns, hi = (sp + 1) * T / ns;

    const int q0 = qt * 64;
    const int qbase = q0 + w * 16;

    const int cA = w * 128 + l;
    const int cB = w * 128 + 64 + l;
    const int keyA = cA >> 3, cbA = (cA & 7) ^ (keyA & 7);
    const int keyB = cB >> 3, cbB = (cB & 7) ^ (keyB & 7);
    const unsigned short* Krow = Kb + (size_t)b * S_LEN * D_DIM + h * DH;
    const unsigned short* Vrow = Vt + (size_t)(b * NHEAD + h) * DH * S_LEN;

    const unsigned short* qptr = Qb + (size_t)(b * S_LEN + qbase + lr) * D_DIM + h * DH + quad * 8;
    const short8 qf0 = *(const short8*)(qptr);
    const short8 qf1 = *(const short8*)(qptr + 32);

    f32x4 zero = {0.f, 0.f, 0.f, 0.f};
    f32x4 o[4];
#pragma unroll
    for (int j = 0; j < 4; j++) o[j] = zero;
    float l_part[4] = {0.f, 0.f, 0.f, 0.f};

    unsigned short* myP = Ps[w];
    const int swz0 = quad ^ (lr & 7);
    const int swz1 = (quad + 4) ^ (lr & 7);

    auto stage = [&](int k0, int bufIdx) {
        __builtin_amdgcn_global_load_lds(
            (const __attribute__((address_space(1))) void*)(Krow + (size_t)(k0 + keyA) * D_DIM + cbA * 8),
            (__attribute__((address_space(3))) void*)(&Ks[bufIdx][(w * 128) * 8]), 16, 0, 0);
        __builtin_amdgcn_global_load_lds(
            (const __attribute__((address_space(1))) void*)(Krow + (size_t)(k0 + keyB) * D_DIM + cbB * 8),
            (__attribute__((address_space(3))) void*)(&Ks[bufIdx][(w * 128 + 64) * 8]), 16, 0, 0);
        __builtin_amdgcn_global_load_lds(
            (const __attribute__((address_space(1))) void*)(Vrow + (size_t)keyA * S_LEN + k0 + cbA * 8),
            (__attribute__((address_space(3))) void*)(&Vs[bufIdx][(w * 128) * 8]), 16, 0, 0);
        __builtin_amdgcn_global_load_lds(
            (const __attribute__((address_space(1))) void*)(Vrow + (size_t)keyB * S_LEN + k0 + cbB * 8),
            (__attribute__((address_space(3))) void*)(&Vs[bufIdx][(w * 128 + 64) * 8]), 16, 0, 0);
    };

    stage(lo * 64, 0);
    __syncthreads();

    for (int kt = lo; kt < hi; ++kt) {
        const int k0 = kt * 64;
        const int cur = (kt - lo) & 1;
        if (kt + 1 < hi) stage((kt + 1) * 64, cur ^ 1);

        float kmv[4];
#pragma unroll
        for (int nf = 0; nf < 4; nf++) kmv[nf] = km_pen[b * S_LEN + k0 + nf * 16 + lr];

        // ---- scores: 16q x 64k (Q pre-scaled) ----
        f32x4 sc[4];
#pragma unroll
        for (int nf = 0; nf < 4; nf++) {
            const int key = nf * 16 + lr;
            const short8 kf0 = *(const short8*)&Ks[cur][(key * 8 + swz0) * 8];
            const short8 kf1 = *(const short8*)&Ks[cur][(key * 8 + swz1) * 8];
            f32x4 z = zero;
            z = __builtin_amdgcn_mfma_f32_16x16x32_bf16(qf0, kf0, z, 0, 0, 0);
            z = __builtin_amdgcn_mfma_f32_16x16x32_bf16(qf1, kf1, z, 0, 0, 0);
            sc[nf] = z;
        }

        // ---- V fragments (independent of P) ----
        short8 vf[2][4];
#pragma unroll
        for (int s = 0; s < 2; s++) {
            const int swz = s ? swz1 : swz0;
#pragma unroll
            for (int j = 0; j < 4; j++)
                vf[s][j] = *(const short8*)&Vs[cur][((j * 16 + lr) * 8 + swz) * 8];
        }

        // ---- softmax: direct exp (bounded scores); causal only on diagonal tile ----
        if (kt == qt) {
#pragma unroll
            for (int r = 0; r < 4; r++) {
                const int row = quad * 4 + r;
                const int q = qbase + row;
                const float v0 = (k0 + lr <= q) ? sc[0][r] + kmv[0] : NEGF;
                const float v1 = (k0 + 16 + lr <= q) ? sc[1][r] + kmv[1] : NEGF;
                const float v2 = (k0 + 32 + lr <= q) ? sc[2][r] + kmv[2] : NEGF;
                const float v3 = (k0 + 48 + lr <= q) ? sc[3][r] + kmv[3] : NEGF;
                const float e0 = __expf(v0);
                const float e1 = __expf(v1);
                const float e2 = __expf(v2);
                const float e3 = __expf(v3);
                l_part[r] += (e0 + e1) + (e2 + e3);
                const int rb = (row & 7);
                const int base = row * 64 + (lr & 7);
                myP[base + (((0 + (lr >> 3)) ^ rb) << 3)] = f2bf_trunc(e0);
                myP[base + (((2 + (lr >> 3)) ^ rb) << 3)] = f2bf_trunc(e1);
                myP[base + (((4 + (lr >> 3)) ^ rb) << 3)] = f2bf_trunc(e2);
                myP[base + (((6 + (lr >> 3)) ^ rb) << 3)] = f2bf_trunc(e3);
            }
        } else {
#pragma unroll
            for (int r = 0; r < 4; r++) {
                const int row = quad * 4 + r;
                const float e0 = __expf(sc[0][r] + kmv[0]);
                const float e1 = __expf(sc[1][r] + kmv[1]);
                const float e2 = __expf(sc[2][r] + kmv[2]);
                const float e3 = __expf(sc[3][r] + kmv[3]);
                l_part[r] += (e0 + e1) + (e2 + e3);
                const int rb = (row & 7);
                const int base = row * 64 + (lr & 7);
                myP[base + (((0 + (lr >> 3)) ^ rb) << 3)] = f2bf_trunc(e0);
                myP[base + (((2 + (lr >> 3)) ^ rb) << 3)] = f2bf_trunc(e1);
                myP[base + (((4 + (lr >> 3)) ^ rb) << 3)] = f2bf_trunc(e2);
                myP[base + (((6 + (lr >> 3)) ^ rb) << 3)] = f2bf_trunc(e3);
            }
        }

        // ---- P (A-layout read) + PV ----
#pragma unroll
        for (int s = 0; s < 2; s++) {
            const short8 pf = *(const short8*)&myP[lr * 64 + (((s * 4 + quad) ^ (lr & 7)) << 3)];
#pragma unroll
            for (int j = 0; j < 4; j++)
                o[j] = __builtin_amdgcn_mfma_f32_16x16x32_bf16(pf, vf[s][j], o[j], 0, 0, 0);
        }
        __syncthreads();
    }

    // ---- epilogue: bf16 O-partials + fp32 l-partials, uniform for all blocks ----
    unsigned short* oP = (sp == 0) ? oP0 : ((sp == 1) ? oP1 : oP2);
#pragma unroll
    for (int r = 0; r < 4; r++) {
        float ls = l_part[r];
        ls += __shfl_xor(ls, 1);
        ls += __shfl_xor(ls, 2);
        ls += __shfl_xor(ls, 4);
        ls += __shfl_xor(ls, 8);
        const int q = qbase + quad * 4 + r;
        if (lr == 0) lP[sp * (BATCH * NHEAD * S_LEN) + (b * NHEAD + h) * S_LEN + q] = ls;
#pragma unroll
        for (int j = 0; j < 4; j++) {
            oP[(size_t)(b * S_LEN + q) * D_DIM + h * DH + j * 16 + lr] = f2bf(o[j][r]);
        }
    }
}

// ---------------- residual + layernorm + split-K combine (up to 3 partials) ------------
__global__ __launch_bounds__(256) void ln_kernel(
    const unsigned short* __restrict__ oP0, const unsigned short* __restrict__ oP1,
    const unsigned short* __restrict__ oP2, const float* __restrict__ lP,
    const float* __restrict__ qmask, const float* __restrict__ queries,
    const float* __restrict__ gamma, const float* __restrict__ beta,
    float* __restrict__ out) {
    const int row = blockIdx.x;
    const int t = threadIdx.x;
    const int b = row >> 11, q = row & 2047;
    const int qt = q >> 6;
    const int ns = (qt <= 10) ? 1 : ((qt <= 21) ? 2 : 3);
    const int h = t >> 4;  // head of this thread's 4 columns
    const int lidx = (b * NHEAD + h) * S_LEN + q;
    const int LSTRIDE = BATCH * NHEAD * S_LEN;

    float ls = lP[lidx];
    const size_t ri = (size_t)row * 256 + t;  // ushort4 index
    const ushort4 a0 = ((const ushort4*)oP0)[ri];
    float sx = bf2f(a0.x), sy = bf2f(a0.y), sz = bf2f(a0.z), sw = bf2f(a0.w);
    if (ns > 1) {
        ls += lP[LSTRIDE + lidx];
        const ushort4 a1 = ((const ushort4*)oP1)[ri];
        sx += bf2f(a1.x); sy += bf2f(a1.y); sz += bf2f(a1.z); sw += bf2f(a1.w);
    }
    if (ns > 2) {
        ls += lP[2 * LSTRIDE + lidx];
        const ushort4 a2 = ((const ushort4*)oP2)[ri];
        sx += bf2f(a2.x); sy += bf2f(a2.y); sz += bf2f(a2.z); sw += bf2f(a2.w);
    }
    const float qmr = qmask[row];
    const float inv0 = (ls > 0.f) ? qmr / ls : 0.f;

    const float4 qv = ((const float4*)(queries + (size_t)row * D_DIM))[t];
    float4 x;
    x.x = sx * inv0 + qv.x;
    x.y = sy * inv0 + qv.y;
    x.z = sz * inv0 + qv.z;
    x.w = sw * inv0 + qv.w;

    float s = x.x + x.y + x.z + x.w;
    float sq = x.x * x.x + x.y * x.y + x.z * x.z + x.w * x.w;
    for (int o = 1; o < 64; o <<= 1) { s += __shfl_xor(s, o); sq += __shfl_xor(sq, o); }
    __shared__ float rs[4], rq[4];
    const int w = t >> 6;
    if ((t & 63) == 0) { rs[w] = s; rq[w] = sq; }
    __syncthreads();
    s = rs[0] + rs[1] + rs[2] + rs[3];
    sq = rq[0] + rq[1] + rq[2] + rq[3];
    const float mean = s * (1.0f / 1024.0f);
    float var = (sq - s * mean) * (1.0f / 1023.0f);
    var = fmaxf(var, 0.f);
    const float inv = 1.0f / (sqrtf(var) + 1e-8f);
    const float4 g = ((const float4*)gamma)[t];
    const float4 bb = ((const float4*)beta)[t];
    float4 y;
    y.x = g.x * (x.x - mean) * inv + bb.x;
    y.y = g.y * (x.y - mean) * inv + bb.y;
    y.z = g.z * (x.z - mean) * inv + bb.z;
    y.w = g.w * (x.w - mean) * inv + bb.w;
    ((float4*)(out + (size_t)row * D_DIM))[t] = y;
}

extern "C" void kernel_launch(void* const* d_in, const int* in_sizes, int n_in, void* d_out,
                              int out_size, void* d_ws, size_t ws_size, hipStream_t stream) {
    const float* queries = (const float*)d_in[0];
    const float* keys = (const float*)d_in[1];
    const float* values = (const float*)d_in[2];
    const float* Wq = (const float*)d_in[3];
    const float* bq = (const float*)d_in[4];
    const float* Wk = (const float*)d_in[5];
    const float* bk = (const float*)d_in[6];
    const float* Wv = (const float*)d_in[7];
    const float* bv = (const float*)d_in[8];
    const float* gamma = (const float*)d_in[9];
    const float* beta = (const float*)d_in[10];
    float* out = (float*)d_out;
    char* ws = (char*)d_ws;

    const size_t MB = 1048576;
    unsigned short* qin = (unsigned short*)(ws + 0);        // dead after proj
    unsigned short* kin = (unsigned short*)(ws + 8 * MB);   // dead after proj
    unsigned short* vin = (unsigned short*)(ws + 16 * MB);  // dead after proj
    unsigned short* wqb = (unsigned short*)(ws + 24 * MB);  // dead after proj
    unsigned short* wkb = (unsigned short*)(ws + 26 * MB);
    unsigned short* wvb = (unsigned short*)(ws + 28 * MB);
    unsigned short* Qb = (unsigned short*)(ws + 30 * MB);
    unsigned short* Kb = (unsigned short*)(ws + 38 * MB);
    unsigned short* Vt = (unsigned short*)(ws + 46 * MB);      // written by proj z==2
    unsigned short* oP0 = (unsigned short*)(ws + 0);           // aliases qin (dead)
    unsigned short* oP1 = (unsigned short*)(ws + 8 * MB);      // aliases kin (dead)
    unsigned short* oP2 = (unsigned short*)(ws + 16 * MB);     // aliases vin (dead)
    float* qm = (float*)(ws + 54 * MB);
    float* km = (float*)(ws + 54 * MB + 16384);
    float* lP = (float*)(ws + 54 * MB + 32768);  // 3 x 2 x 16 x 2048 fp32 = 768KB

    cvt_all_kernel<<<dim3(NROWS + D_DIM, 3), 256, 0, stream>>>(
        queries, keys, values, Wq, Wk, Wv, qin, kin, vin, wqb, wkb, wvb, qm, km);

    proj_kernel<<<dim3(D_DIM / 128, NROWS / 128, 3), 256, 0, stream>>>(
        qin, kin, vin, wqb, wkb, wvb, bq, bk, bv, Qb, Kb, Vt);

    attn_kernel<<<dim3(63, NHEAD, BATCH), 256, 0, stream>>>(Qb, Kb, Vt, km, oP0, oP1, oP2, lP);

    ln_kernel<<<NROWS, 256, 0, stream>>>(oP0, oP1, oP2, lP, qm, queries, gamma, beta, out);
}

// Round 6
// 211.484 us; speedup vs baseline: 1.9940x; 1.0187x over previous
//
#include <hip/hip_runtime.h>

#define S_LEN 2048
#define D_DIM 1024
#define NHEAD 16
#define DH 64
#define BATCH 2
#define NROWS (BATCH * S_LEN)  // 4096
#define QSCALE 0.18033688011112042f  // 0.125 * log2(e): scores land in log2 domain

typedef __attribute__((ext_vector_type(8))) short short8;
typedef __attribute__((ext_vector_type(4))) float f32x4;

static __device__ __forceinline__ unsigned short f2bf(float f) {
    unsigned int u = __builtin_bit_cast(unsigned int, f);
    u += 0x7fffu + ((u >> 16) & 1u);
    return (unsigned short)(u >> 16);
}
static __device__ __forceinline__ float bf2f(unsigned short h) {
    unsigned int u = ((unsigned int)h) << 16;
    return __builtin_bit_cast(float, u);
}
static __device__ __forceinline__ unsigned short f2bf_trunc(float f) {
    return (unsigned short)(__builtin_bit_cast(unsigned int, f) >> 16);
}

// ---------------- fp32 -> bf16 convert (inputs + weights) + fused padding masks --------
__global__ __launch_bounds__(256) void cvt_all_kernel(
    const float* __restrict__ s0, const float* __restrict__ s1, const float* __restrict__ s2,
    const float* __restrict__ w0, const float* __restrict__ w1, const float* __restrict__ w2,
    unsigned short* __restrict__ d0, unsigned short* __restrict__ d1,
    unsigned short* __restrict__ d2, unsigned short* __restrict__ e0,
    unsigned short* __restrict__ e1, unsigned short* __restrict__ e2,
    float* __restrict__ qm, float* __restrict__ km) {
    const int y = blockIdx.y;
    const int row = blockIdx.x;
    const int t = threadIdx.x;
    const float* src;
    unsigned short* dst;
    size_t i;
    if (row < NROWS) {
        src = y == 0 ? s0 : (y == 1 ? s1 : s2);
        dst = y == 0 ? d0 : (y == 1 ? d1 : d2);
        i = (size_t)row * 256 + t;
    } else {
        src = y == 0 ? w0 : (y == 1 ? w1 : w2);
        dst = y == 0 ? e0 : (y == 1 ? e1 : e2);
        i = (size_t)(row - NROWS) * 256 + t;
    }
    float4 v = ((const float4*)src)[i];
    ushort4 o;
    o.x = f2bf(v.x); o.y = f2bf(v.y); o.z = f2bf(v.z); o.w = f2bf(v.w);
    ((ushort4*)dst)[i] = o;
    if (row < NROWS && y < 2) {
        float s = v.x + v.y + v.z + v.w;
        for (int off = 1; off < 64; off <<= 1) s += __shfl_xor(s, off);
        __shared__ float red[4];
        const int w = t >> 6;
        if ((t & 63) == 0) red[w] = s;
        __syncthreads();
        if (t == 0) {
            float tt = red[0] + red[1] + red[2] + red[3];
            if (y == 0)
                qm[row] = (tt != 0.0f) ? 1.0f : 0.0f;
            else
                km[row] = (tt != 0.0f) ? 0.0f : -4294967295.0f;
        }
    }
}

// ---------------- fused QKV projection: O = relu(A @ W^T + b), bf16 MFMA ----------------
// z==0 (Q): output scaled by QSCALE (attention scale + log2e for exp2 softmax).
// All outputs row-major (B,S,D).
__global__ __launch_bounds__(256) void proj_kernel(
    const unsigned short* __restrict__ A0, const unsigned short* __restrict__ A1,
    const unsigned short* __restrict__ A2, const unsigned short* __restrict__ W0,
    const unsigned short* __restrict__ W1, const unsigned short* __restrict__ W2,
    const float* __restrict__ b0, const float* __restrict__ b1, const float* __restrict__ b2,
    unsigned short* __restrict__ O0, unsigned short* __restrict__ O1,
    unsigned short* __restrict__ O2) {
    const unsigned short* A;
    const unsigned short* W;
    const float* bias;
    unsigned short* O;
    if (blockIdx.z == 0) { A = A0; W = W0; bias = b0; O = O0; }
    else if (blockIdx.z == 1) { A = A1; W = W1; bias = b1; O = O1; }
    else { A = A2; W = W2; bias = b2; O = O2; }

    __shared__ __align__(16) unsigned short Asm[128 * 32];
    __shared__ __align__(16) unsigned short Bsm[128 * 32];

    const int t = threadIdx.x;
    const int w = t >> 6, l = t & 63;
    const int quad = l >> 4, lr = l & 15;
    const int wm = w >> 1, wn = w & 1;
    const int m0 = blockIdx.y * 128, n0 = blockIdx.x * 128;

    f32x4 zero = {0.f, 0.f, 0.f, 0.f};
    f32x4 acc[4][4];
#pragma unroll
    for (int i = 0; i < 4; i++)
#pragma unroll
        for (int j = 0; j < 4; j++) acc[i][j] = zero;

    const int c0 = w * 2, c1 = w * 2 + 1;
    const int ar0 = c0 * 16 + (l >> 2), ar1 = c1 * 16 + (l >> 2);
    const int acol = (l & 3) * 8;

    for (int kt = 0; kt < D_DIM / 32; ++kt) {
        const int k0 = kt * 32;
        __syncthreads();
        __builtin_amdgcn_global_load_lds(
            (const __attribute__((address_space(1))) void*)(A + (size_t)(m0 + ar0) * D_DIM + k0 + acol),
            (__attribute__((address_space(3))) void*)(&Asm[c0 * 512]), 16, 0, 0);
        __builtin_amdgcn_global_load_lds(
            (const __attribute__((address_space(1))) void*)(A + (size_t)(m0 + ar1) * D_DIM + k0 + acol),
            (__attribute__((address_space(3))) void*)(&Asm[c1 * 512]), 16, 0, 0);
        __builtin_amdgcn_global_load_lds(
            (const __attribute__((address_space(1))) void*)(W + (size_t)(n0 + ar0) * D_DIM + k0 + acol),
            (__attribute__((address_space(3))) void*)(&Bsm[c0 * 512]), 16, 0, 0);
        __builtin_amdgcn_global_load_lds(
            (const __attribute__((address_space(1))) void*)(W + (size_t)(n0 + ar1) * D_DIM + k0 + acol),
            (__attribute__((address_space(3))) void*)(&Bsm[c1 * 512]), 16, 0, 0);
        __syncthreads();

        short8 af[4], bf[4];
#pragma unroll
        for (int i = 0; i < 4; i++)
            af[i] = *(const short8*)&Asm[(wm * 64 + i * 16 + lr) * 32 + quad * 8];
#pragma unroll
        for (int j = 0; j < 4; j++)
            bf[j] = *(const short8*)&Bsm[(wn * 64 + j * 16 + lr) * 32 + quad * 8];
#pragma unroll
        for (int i = 0; i < 4; i++)
#pragma unroll
            for (int j = 0; j < 4; j++)
                acc[i][j] = __builtin_amdgcn_mfma_f32_16x16x32_bf16(af[i], bf[j], acc[i][j], 0, 0, 0);
    }

    const float oscale = (blockIdx.z == 0) ? QSCALE : 1.0f;
#pragma unroll
    for (int j = 0; j < 4; j++) {
        const int gn = n0 + wn * 64 + j * 16 + lr;
        const float bj = bias[gn];
#pragma unroll
        for (int i = 0; i < 4; i++) {
            const int gmb = m0 + wm * 64 + i * 16 + quad * 4;
#pragma unroll
            for (int r = 0; r < 4; r++) {
                float v = fmaxf(acc[i][j][r] + bj, 0.f) * oscale;
                O[(size_t)(gmb + r) * D_DIM + gn] = f2bf(v);
            }
        }
    }
}

// ---------------- V transpose: (B,S,D) bf16 -> (B,H,dh,S) bf16 (coalesced both ways) ----
__global__ __launch_bounds__(256) void transpose_v(const unsigned short* __restrict__ Vb,
                                                   unsigned short* __restrict__ Vt) {
    __shared__ unsigned short tile[64][65];
    const int s0 = blockIdx.x * 64, h = blockIdx.y, b = blockIdx.z;
    const int t = threadIdx.x;
#pragma unroll
    for (int p = 0; p < 16; p++) {
        int idx = p * 256 + t;
        int si = idx >> 6, ni = idx & 63;
        tile[si][ni] = Vb[(size_t)(b * S_LEN + s0 + si) * D_DIM + h * DH + ni];
    }
    __syncthreads();
#pragma unroll
    for (int p = 0; p < 16; p++) {
        int idx = p * 256 + t;
        int ni = idx >> 6, si = idx & 63;
        Vt[((size_t)(b * NHEAD + h) * DH + ni) * S_LEN + s0 + si] = tile[si][ni];
    }
}

// ---------------- flash attention: exp2 softmax, split-K, single-buffered V -------------
// grid (63, H, B). LDS = Ks[2] 16KB + Vs 8KB + Ps 8KB = 32768 B -> 5 blocks/CU.
// Per tile: [B1] prefetch K(kt+1), stage V(kt); QK on Ks[cur]; softmax; [B2: vmcnt drain
// guarantees V staged]; PV. Q pre-scaled by 0.125*log2e so softmax is bare exp2.
__global__ __launch_bounds__(256) void attn_kernel(
    const unsigned short* __restrict__ Qb, const unsigned short* __restrict__ Kb,
    const unsigned short* __restrict__ Vt, const float* __restrict__ km_pen,
    unsigned short* __restrict__ oP0, unsigned short* __restrict__ oP1,
    unsigned short* __restrict__ oP2, float* __restrict__ lP) {
    __shared__ __align__(16) unsigned short Ks[2][64 * 64];
    __shared__ __align__(16) unsigned short Vs[64 * 64];
    __shared__ __align__(16) unsigned short Ps[4][16 * 64];

    const int w = threadIdx.x >> 6, l = threadIdx.x & 63;
    const int quad = l >> 4, lr = l & 15;
    const int h = blockIdx.y, b = blockIdx.z;
    const float NEGF = -4294967295.0f;

    // ---- work assignment (LPT: longest first) ----
    int qt, sp;
    const int x = blockIdx.x;
    int ns;
    if (x < 30) { qt = 31 - x / 3; sp = x % 3; ns = 3; }
    else if (x < 52) { int y = x - 30; qt = 21 - y / 2; sp = y % 2; ns = 2; }
    else { qt = 62 - x; sp = 0; ns = 1; }
    const int T = qt + 1;
    const int lo = sp * T / ns, hi = (sp + 1) * T / ns;

    const int q0 = qt * 64;
    const int qbase = q0 + w * 16;

    const int cA = w * 128 + l;
    const int cB = w * 128 + 64 + l;
    const int keyA = cA >> 3, cbA = (cA & 7) ^ (keyA & 7);
    const int keyB = cB >> 3, cbB = (cB & 7) ^ (keyB & 7);
    const unsigned short* Krow = Kb + (size_t)b * S_LEN * D_DIM + h * DH;
    const unsigned short* Vrow = Vt + (size_t)(b * NHEAD + h) * DH * S_LEN;

    // incremental staging pointers (advance per tile; no per-tile addr recompute)
    const unsigned short* kSA = Krow + (size_t)(lo * 64 + keyA) * D_DIM + cbA * 8;
    const unsigned short* kSB = Krow + (size_t)(lo * 64 + keyB) * D_DIM + cbB * 8;
    const unsigned short* vSA = Vrow + (size_t)keyA * S_LEN + lo * 64 + cbA * 8;
    const unsigned short* vSB = Vrow + (size_t)keyB * S_LEN + lo * 64 + cbB * 8;
    const float* kmp = km_pen + b * S_LEN + lo * 64 + lr;

    unsigned short* const kD0 = &Ks[0][(w * 128) * 8];
    unsigned short* const kD1 = &Ks[0][(w * 128 + 64) * 8];
    unsigned short* const kE0 = &Ks[1][(w * 128) * 8];
    unsigned short* const kE1 = &Ks[1][(w * 128 + 64) * 8];
    unsigned short* const vD0 = &Vs[(w * 128) * 8];
    unsigned short* const vD1 = &Vs[(w * 128 + 64) * 8];

    const unsigned short* qptr = Qb + (size_t)(b * S_LEN + qbase + lr) * D_DIM + h * DH + quad * 8;
    const short8 qf0 = *(const short8*)(qptr);
    const short8 qf1 = *(const short8*)(qptr + 32);

    f32x4 zero = {0.f, 0.f, 0.f, 0.f};
    f32x4 o[4];
#pragma unroll
    for (int j = 0; j < 4; j++) o[j] = zero;
    float l_part[4] = {0.f, 0.f, 0.f, 0.f};

    unsigned short* myP = Ps[w];
    const int swz0 = quad ^ (lr & 7);
    const int swz1 = (quad + 4) ^ (lr & 7);

#define GLDS(src, dst)                                                                  \
    __builtin_amdgcn_global_load_lds((const __attribute__((address_space(1))) void*)(src), \
                                     (__attribute__((address_space(3))) void*)(dst), 16, 0, 0)

    // stage K(lo) into Ks[0]
    GLDS(kSA, kD0);
    GLDS(kSB, kD1);
    kSA += 64 * D_DIM;
    kSB += 64 * D_DIM;

    for (int kt = lo; kt < hi; ++kt) {
        const int cur = (kt - lo) & 1;
        __syncthreads();  // B1: prev PV reads of Vs done; K(cur) staged (vmcnt drained here)
        if (kt + 1 < hi) {
            if (cur) { GLDS(kSA, kD0); GLDS(kSB, kD1); }
            else     { GLDS(kSA, kE0); GLDS(kSB, kE1); }
            kSA += 64 * D_DIM;
            kSB += 64 * D_DIM;
        }
        GLDS(vSA, vD0);
        GLDS(vSB, vD1);
        vSA += 64;
        vSB += 64;

        float kmv[4];
#pragma unroll
        for (int nf = 0; nf < 4; nf++) kmv[nf] = kmp[nf * 16];
        kmp += 64;

        // ---- scores (log2 domain): 16q x 64k ----
        f32x4 sc[4];
#pragma unroll
        for (int nf = 0; nf < 4; nf++) {
            const int key = nf * 16 + lr;
            const short8 kf0 = *(const short8*)&Ks[cur][(key * 8 + swz0) * 8];
            const short8 kf1 = *(const short8*)&Ks[cur][(key * 8 + swz1) * 8];
            f32x4 z = zero;
            z = __builtin_amdgcn_mfma_f32_16x16x32_bf16(qf0, kf0, z, 0, 0, 0);
            z = __builtin_amdgcn_mfma_f32_16x16x32_bf16(qf1, kf1, z, 0, 0, 0);
            sc[nf] = z;
        }

        // ---- softmax: bare exp2 (scores bounded); causal only on diagonal tile ----
        if (kt == qt) {
            const int k0 = kt * 64;
#pragma unroll
            for (int r = 0; r < 4; r++) {
                const int row = quad * 4 + r;
                const int q = qbase + row;
                const float v0 = (k0 + lr <= q) ? sc[0][r] + kmv[0] : NEGF;
                const float v1 = (k0 + 16 + lr <= q) ? sc[1][r] + kmv[1] : NEGF;
                const float v2 = (k0 + 32 + lr <= q) ? sc[2][r] + kmv[2] : NEGF;
                const float v3 = (k0 + 48 + lr <= q) ? sc[3][r] + kmv[3] : NEGF;
                const float e0 = exp2f(v0);
                const float e1 = exp2f(v1);
                const float e2 = exp2f(v2);
                const float e3 = exp2f(v3);
                l_part[r] += (e0 + e1) + (e2 + e3);
                const int rb = (row & 7);
                const int base = row * 64 + (lr & 7);
                myP[base + (((0 + (lr >> 3)) ^ rb) << 3)] = f2bf_trunc(e0);
                myP[base + (((2 + (lr >> 3)) ^ rb) << 3)] = f2bf_trunc(e1);
                myP[base + (((4 + (lr >> 3)) ^ rb) << 3)] = f2bf_trunc(e2);
                myP[base + (((6 + (lr >> 3)) ^ rb) << 3)] = f2bf_trunc(e3);
            }
        } else {
#pragma unroll
            for (int r = 0; r < 4; r++) {
                const int row = quad * 4 + r;
                const float e0 = exp2f(sc[0][r] + kmv[0]);
                const float e1 = exp2f(sc[1][r] + kmv[1]);
                const float e2 = exp2f(sc[2][r] + kmv[2]);
                const float e3 = exp2f(sc[3][r] + kmv[3]);
                l_part[r] += (e0 + e1) + (e2 + e3);
                const int rb = (row & 7);
                const int base = row * 64 + (lr & 7);
                myP[base + (((0 + (lr >> 3)) ^ rb) << 3)] = f2bf_trunc(e0);
                myP[base + (((2 + (lr >> 3)) ^ rb) << 3)] = f2bf_trunc(e1);
                myP[base + (((4 + (lr >> 3)) ^ rb) << 3)] = f2bf_trunc(e2);
                myP[base + (((6 + (lr >> 3)) ^ rb) << 3)] = f2bf_trunc(e3);
            }
        }

        __syncthreads();  // B2: vmcnt(0) drain => V(kt) staged by all waves

        // ---- V fragments + P (A-layout) + PV ----
#pragma unroll
        for (int s = 0; s < 2; s++) {
            const int swz = s ? swz1 : swz0;
            const short8 pf = *(const short8*)&myP[lr * 64 + (((s * 4 + quad) ^ (lr & 7)) << 3)];
#pragma unroll
            for (int j = 0; j < 4; j++) {
                const short8 vfj = *(const short8*)&Vs[((j * 16 + lr) * 8 + swz) * 8];
                o[j] = __builtin_amdgcn_mfma_f32_16x16x32_bf16(pf, vfj, o[j], 0, 0, 0);
            }
        }
    }
#undef GLDS

    // ---- epilogue: bf16 O-partials + fp32 l-partials ----
    unsigned short* oP = (sp == 0) ? oP0 : ((sp == 1) ? oP1 : oP2);
#pragma unroll
    for (int r = 0; r < 4; r++) {
        float ls = l_part[r];
        ls += __shfl_xor(ls, 1);
        ls += __shfl_xor(ls, 2);
        ls += __shfl_xor(ls, 4);
        ls += __shfl_xor(ls, 8);
        const int q = qbase + quad * 4 + r;
        if (lr == 0) lP[sp * (BATCH * NHEAD * S_LEN) + (b * NHEAD + h) * S_LEN + q] = ls;
#pragma unroll
        for (int j = 0; j < 4; j++) {
            oP[(size_t)(b * S_LEN + q) * D_DIM + h * DH + j * 16 + lr] = f2bf(o[j][r]);
        }
    }
}

// ---------------- residual + layernorm + split-K combine (up to 3 partials) ------------
__global__ __launch_bounds__(256) void ln_kernel(
    const unsigned short* __restrict__ oP0, const unsigned short* __restrict__ oP1,
    const unsigned short* __restrict__ oP2, const float* __restrict__ lP,
    const float* __restrict__ qmask, const float* __restrict__ queries,
    const float* __restrict__ gamma, const float* __restrict__ beta,
    float* __restrict__ out) {
    const int row = blockIdx.x;
    const int t = threadIdx.x;
    const int b = row >> 11, q = row & 2047;
    const int qt = q >> 6;
    const int ns = (qt <= 10) ? 1 : ((qt <= 21) ? 2 : 3);
    const int h = t >> 4;
    const int lidx = (b * NHEAD + h) * S_LEN + q;
    const int LSTRIDE = BATCH * NHEAD * S_LEN;

    float ls = lP[lidx];
    const size_t ri = (size_t)row * 256 + t;
    const ushort4 a0 = ((const ushort4*)oP0)[ri];
    float sx = bf2f(a0.x), sy = bf2f(a0.y), sz = bf2f(a0.z), sw = bf2f(a0.w);
    if (ns > 1) {
        ls += lP[LSTRIDE + lidx];
        const ushort4 a1 = ((const ushort4*)oP1)[ri];
        sx += bf2f(a1.x); sy += bf2f(a1.y); sz += bf2f(a1.z); sw += bf2f(a1.w);
    }
    if (ns > 2) {
        ls += lP[2 * LSTRIDE + lidx];
        const ushort4 a2 = ((const ushort4*)oP2)[ri];
        sx += bf2f(a2.x); sy += bf2f(a2.y); sz += bf2f(a2.z); sw += bf2f(a2.w);
    }
    const float qmr = qmask[row];
    const float inv0 = (ls > 0.f) ? qmr / ls : 0.f;

    const float4 qv = ((const float4*)(queries + (size_t)row * D_DIM))[t];
    float4 x;
    x.x = sx * inv0 + qv.x;
    x.y = sy * inv0 + qv.y;
    x.z = sz * inv0 + qv.z;
    x.w = sw * inv0 + qv.w;

    float s = x.x + x.y + x.z + x.w;
    float sq = x.x * x.x + x.y * x.y + x.z * x.z + x.w * x.w;
    for (int o = 1; o < 64; o <<= 1) { s += __shfl_xor(s, o); sq += __shfl_xor(sq, o); }
    __shared__ float rs[4], rq[4];
    const int w = t >> 6;
    if ((t & 63) == 0) { rs[w] = s; rq[w] = sq; }
    __syncthreads();
    s = rs[0] + rs[1] + rs[2] + rs[3];
    sq = rq[0] + rq[1] + rq[2] + rq[3];
    const float mean = s * (1.0f / 1024.0f);
    float var = (sq - s * mean) * (1.0f / 1023.0f);
    var = fmaxf(var, 0.f);
    const float inv = 1.0f / (sqrtf(var) + 1e-8f);
    const float4 g = ((const float4*)gamma)[t];
    const float4 bb = ((const float4*)beta)[t];
    float4 y;
    y.x = g.x * (x.x - mean) * inv + bb.x;
    y.y = g.y * (x.y - mean) * inv + bb.y;
    y.z = g.z * (x.z - mean) * inv + bb.z;
    y.w = g.w * (x.w - mean) * inv + bb.w;
    ((float4*)(out + (size_t)row * D_DIM))[t] = y;
}

extern "C" void kernel_launch(void* const* d_in, const int* in_sizes, int n_in, void* d_out,
                              int out_size, void* d_ws, size_t ws_size, hipStream_t stream) {
    const float* queries = (const float*)d_in[0];
    const float* keys = (const float*)d_in[1];
    const float* values = (const float*)d_in[2];
    const float* Wq = (const float*)d_in[3];
    const float* bq = (const float*)d_in[4];
    const float* Wk = (const float*)d_in[5];
    const float* bk = (const float*)d_in[6];
    const float* Wv = (const float*)d_in[7];
    const float* bv = (const float*)d_in[8];
    const float* gamma = (const float*)d_in[9];
    const float* beta = (const float*)d_in[10];
    float* out = (float*)d_out;
    char* ws = (char*)d_ws;

    const size_t MB = 1048576;
    // phase 1 (cvt+proj):    qin 0-8, kin 8-16, vin 16-24, w 24-30, Qb 30-38, Kb 38-46, Vb 46-54
    // phase 2 (transpose):   Vt 0-8 (ex-qin, dead)
    // phase 3 (attn):        oP0 16-24 (ex-vin), oP1 46-54 (ex-Vb), oP2 8-16 (ex-kin)
    unsigned short* qin = (unsigned short*)(ws + 0);
    unsigned short* kin = (unsigned short*)(ws + 8 * MB);
    unsigned short* vin = (unsigned short*)(ws + 16 * MB);
    unsigned short* wqb = (unsigned short*)(ws + 24 * MB);
    unsigned short* wkb = (unsigned short*)(ws + 26 * MB);
    unsigned short* wvb = (unsigned short*)(ws + 28 * MB);
    unsigned short* Qb = (unsigned short*)(ws + 30 * MB);
    unsigned short* Kb = (unsigned short*)(ws + 38 * MB);
    unsigned short* Vb = (unsigned short*)(ws + 46 * MB);
    unsigned short* Vt = (unsigned short*)(ws + 0);
    unsigned short* oP0 = (unsigned short*)(ws + 16 * MB);
    unsigned short* oP1 = (unsigned short*)(ws + 46 * MB);
    unsigned short* oP2 = (unsigned short*)(ws + 8 * MB);
    float* qm = (float*)(ws + 54 * MB);
    float* km = (float*)(ws + 54 * MB + 16384);
    float* lP = (float*)(ws + 54 * MB + 32768);  // 3 x 65536 fp32 = 768KB

    cvt_all_kernel<<<dim3(NROWS + D_DIM, 3), 256, 0, stream>>>(
        queries, keys, values, Wq, Wk, Wv, qin, kin, vin, wqb, wkb, wvb, qm, km);

    proj_kernel<<<dim3(D_DIM / 128, NROWS / 128, 3), 256, 0, stream>>>(
        qin, kin, vin, wqb, wkb, wvb, bq, bk, bv, Qb, Kb, Vb);

    transpose_v<<<dim3(S_LEN / 64, NHEAD, BATCH), 256, 0, stream>>>(Vb, Vt);

    attn_kernel<<<dim3(63, NHEAD, BATCH), 256, 0, stream>>>(Qb, Kb, Vt, km, oP0, oP1, oP2, lP);

    ln_kernel<<<NROWS, 256, 0, stream>>>(oP0, oP1, oP2, lP, qm, queries, gamma, beta, out);
}